// Round 1
// baseline (1142.499 us; speedup 1.0000x reference)
//
#include <hip/hip_runtime.h>
#include <math.h>

#define S_LEN 1024
#define B_SZ 4
#define E_DIM 1024
#define H_NUM 16
#define HD 64
#define IDX_MAX 2044   // clip(dist,-1022,1022)+1022 in [0,2044]
#define NEG_BIG (-3.0e38f)

__device__ __forceinline__ int permrow(int r) {
  // bijective within each 8-row stripe; spreads stride-4-row reads across banks
  return (r & ~7) | ((r + (r >> 3)) & 7);
}

// ---------------------------------------------------------------------------
// C = X[4096x1024] @ W^T + bias, fp32, tile 128x128, 256 thr, 8x8 per thread
// mode 0: X rows are (s*B+b) [query/key/value layout]; out -> [B,H,S,hd]*scale
// mode 1: X rows are (b*S+s) [attn buffer B,S,E];      out -> [S,B,E]
// ---------------------------------------------------------------------------
__global__ __launch_bounds__(256) void proj_gemm(
    const float* __restrict__ X, const float* __restrict__ W,
    const float* __restrict__ bias, float* __restrict__ out,
    float scale, int mode)
{
  __shared__ float Xs[16][132];
  __shared__ float Ws[16][132];

  const int tid = threadIdx.x;
  const int m0 = blockIdx.x << 7;
  const int n0 = blockIdx.y << 7;
  const int tr = tid >> 4;   // 0..15
  const int tc = tid & 15;   // 0..15

  float acc[8][8];
#pragma unroll
  for (int i = 0; i < 8; ++i)
#pragma unroll
    for (int j = 0; j < 8; ++j) acc[i][j] = 0.f;

  const int ldRow = tid >> 2;        // 0..63
  const int ldK   = (tid & 3) << 2;  // 0,4,8,12

  const float* Xp = X + (size_t)(m0 + ldRow) * E_DIM + ldK;
  const float* Wp = W + (size_t)(n0 + ldRow) * E_DIM + ldK;

  for (int kb = 0; kb < 64; ++kb) {
    const int k0 = kb << 4;
    const float4 xa = *(const float4*)(Xp + k0);
    const float4 xb = *(const float4*)(Xp + k0 + (size_t)64 * E_DIM);
    const float4 wa = *(const float4*)(Wp + k0);
    const float4 wb = *(const float4*)(Wp + k0 + (size_t)64 * E_DIM);
    __syncthreads();   // protect previous iteration's LDS reads
    Xs[ldK + 0][ldRow] = xa.x; Xs[ldK + 1][ldRow] = xa.y;
    Xs[ldK + 2][ldRow] = xa.z; Xs[ldK + 3][ldRow] = xa.w;
    Xs[ldK + 0][ldRow + 64] = xb.x; Xs[ldK + 1][ldRow + 64] = xb.y;
    Xs[ldK + 2][ldRow + 64] = xb.z; Xs[ldK + 3][ldRow + 64] = xb.w;
    Ws[ldK + 0][ldRow] = wa.x; Ws[ldK + 1][ldRow] = wa.y;
    Ws[ldK + 2][ldRow] = wa.z; Ws[ldK + 3][ldRow] = wa.w;
    Ws[ldK + 0][ldRow + 64] = wb.x; Ws[ldK + 1][ldRow + 64] = wb.y;
    Ws[ldK + 2][ldRow + 64] = wb.z; Ws[ldK + 3][ldRow + 64] = wb.w;
    __syncthreads();
#pragma unroll
    for (int kk = 0; kk < 16; ++kk) {
      const float4 x0 = *(const float4*)&Xs[kk][tr << 2];
      const float4 x1 = *(const float4*)&Xs[kk][(tr << 2) + 64];
      const float4 w0 = *(const float4*)&Ws[kk][tc << 2];
      const float4 w1 = *(const float4*)&Ws[kk][(tc << 2) + 64];
      const float xr[8] = {x0.x, x0.y, x0.z, x0.w, x1.x, x1.y, x1.z, x1.w};
      const float wr[8] = {w0.x, w0.y, w0.z, w0.w, w1.x, w1.y, w1.z, w1.w};
#pragma unroll
      for (int i = 0; i < 8; ++i)
#pragma unroll
        for (int j = 0; j < 8; ++j)
          acc[i][j] = fmaf(xr[i], wr[j], acc[i][j]);
    }
  }

#pragma unroll
  for (int i = 0; i < 8; ++i) {
    const int m = m0 + (tr << 2) + (i & 3) + ((i >> 2) << 6);
#pragma unroll
    for (int jh = 0; jh < 2; ++jh) {
      const int n = n0 + (tc << 2) + (jh << 6);
      const float4 bv = *(const float4*)(bias + n);
      float4 v;
      v.x = (acc[i][jh * 4 + 0] + bv.x) * scale;
      v.y = (acc[i][jh * 4 + 1] + bv.y) * scale;
      v.z = (acc[i][jh * 4 + 2] + bv.z) * scale;
      v.w = (acc[i][jh * 4 + 3] + bv.w) * scale;
      size_t off;
      if (mode == 0) {
        const int s = m >> 2, b = m & 3;
        const int h = n >> 6, d = n & 63;
        off = ((((size_t)b * H_NUM + h) * S_LEN) + s) * HD + d;
      } else {
        const int b = m >> 10, s = m & 1023;
        off = ((size_t)s * B_SZ + b) * E_DIM + n;
      }
      *(float4*)(out + off) = v;
    }
  }
}

// ---------------------------------------------------------------------------
// Flash-style attention with relative position bias.
// Block: one (b,h), 64 q-rows. 256 thr, thread tile 4x4. t-tiles of 64.
// score[i][j] = q[i]·k[j] + q[i]·rel[j-i+63]   (q pre-scaled)
// ---------------------------------------------------------------------------
__global__ __launch_bounds__(256) void attn_rel(
    const float* __restrict__ Q, const float* __restrict__ Kb,
    const float* __restrict__ Vb, const float* __restrict__ Tb,
    float* __restrict__ AO)
{
  __shared__ float qs[64][68];
  __shared__ float ks[64][68];     // row-permuted
  __shared__ float vs[64][68];
  __shared__ float rel[128][68];   // row-permuted band of the table
  __shared__ float ps[64][68];     // softmax probabilities

  const int tid = threadIdx.x;
  const int st = blockIdx.x & 15;
  const int bh = blockIdx.x >> 4;
  const int s0 = st << 6;
  const int b = bh >> 4;
  const int h = bh & 15;
  const float* Qp = Q + (size_t)bh * S_LEN * HD;
  const float* Kp = Kb + (size_t)bh * S_LEN * HD;
  const float* Vp = Vb + (size_t)bh * S_LEN * HD;

  // load q tile (64x64)
  {
    const int r = tid >> 2;
    const int c = (tid & 3) << 4;
    const float* src = Qp + (size_t)(s0 + r) * HD + c;
    const float4 a0 = *(const float4*)(src);
    const float4 a1 = *(const float4*)(src + 4);
    const float4 a2 = *(const float4*)(src + 8);
    const float4 a3 = *(const float4*)(src + 12);
    *(float4*)&qs[r][c]      = a0;
    *(float4*)&qs[r][c + 4]  = a1;
    *(float4*)&qs[r][c + 8]  = a2;
    *(float4*)&qs[r][c + 12] = a3;
  }

  const int ti = tid >> 4, tj = tid & 15;
  const int i0 = ti << 2, j0 = tj << 2;
  const int d0 = tj << 2;

  float o[4][4];
  float mrow[4], lrow[4];
#pragma unroll
  for (int i = 0; i < 4; ++i) {
    mrow[i] = NEG_BIG; lrow[i] = 0.f;
#pragma unroll
    for (int j = 0; j < 4; ++j) o[i][j] = 0.f;
  }

  int kr[4];
#pragma unroll
  for (int jj = 0; jj < 4; ++jj) kr[jj] = permrow(j0 + jj);
  const int rb = j0 - i0 + 60;   // rel row for (ii=3,jj=0); u = jj-ii+3 in 0..6
  int rr[7];
#pragma unroll
  for (int u = 0; u < 7; ++u) rr[u] = permrow(rb + u);

  for (int tt = 0; tt < 16; ++tt) {
    const int t0 = tt << 6;
    __syncthreads();   // previous PV / score reads finished

    // stage K,V (64x64 each)
    {
      const int r = tid >> 2;
      const int c = (tid & 3) << 4;
      const float* ksrc = Kp + (size_t)(t0 + r) * HD + c;
      const float* vsrc = Vp + (size_t)(t0 + r) * HD + c;
      const float4 ka = *(const float4*)(ksrc);
      const float4 k1 = *(const float4*)(ksrc + 4);
      const float4 k2 = *(const float4*)(ksrc + 8);
      const float4 k3 = *(const float4*)(ksrc + 12);
      const float4 va = *(const float4*)(vsrc);
      const float4 v1 = *(const float4*)(vsrc + 4);
      const float4 v2 = *(const float4*)(vsrc + 8);
      const float4 v3 = *(const float4*)(vsrc + 12);
      const int pr = permrow(r);
      *(float4*)&ks[pr][c]      = ka;
      *(float4*)&ks[pr][c + 4]  = k1;
      *(float4*)&ks[pr][c + 8]  = k2;
      *(float4*)&ks[pr][c + 12] = k3;
      *(float4*)&vs[r][c]      = va;
      *(float4*)&vs[r][c + 4]  = v1;
      *(float4*)&vs[r][c + 8]  = v2;
      *(float4*)&vs[r][c + 12] = v3;
    }
    // stage rel band: logical rows 0..127 (127 is a safe dummy -> perm 126)
    {
      const int rbase = t0 - s0 + 959;   // t0-s0-63+1022
#pragma unroll
      for (int l = 0; l < 8; ++l) {
        const int it = tid + (l << 8);
        const int r = it >> 4;
        const int c = (it & 15) << 2;
        int g = rbase + r;
        g = g < 0 ? 0 : (g > IDX_MAX ? IDX_MAX : g);
        *(float4*)&rel[permrow(r)][c] = *(const float4*)(Tb + (size_t)g * HD + c);
      }
    }
    __syncthreads();

    // scores: content + positional, fused
    float acc[4][4];
#pragma unroll
    for (int i = 0; i < 4; ++i)
#pragma unroll
      for (int j = 0; j < 4; ++j) acc[i][j] = 0.f;

#pragma unroll 4
    for (int d4 = 0; d4 < 16; ++d4) {
      const int d = d4 << 2;
      float4 qv[4], kv[4], rv[7];
#pragma unroll
      for (int ii = 0; ii < 4; ++ii) qv[ii] = *(const float4*)&qs[i0 + ii][d];
#pragma unroll
      for (int jj = 0; jj < 4; ++jj) kv[jj] = *(const float4*)&ks[kr[jj]][d];
#pragma unroll
      for (int u = 0; u < 7; ++u) rv[u] = *(const float4*)&rel[rr[u]][d];
#pragma unroll
      for (int ii = 0; ii < 4; ++ii)
#pragma unroll
        for (int jj = 0; jj < 4; ++jj) {
          const float4 q = qv[ii];
          const float4 k = kv[jj];
          const float4 t = rv[jj - ii + 3];
          float a = acc[ii][jj];
          a = fmaf(q.x, k.x, a); a = fmaf(q.y, k.y, a);
          a = fmaf(q.z, k.z, a); a = fmaf(q.w, k.w, a);
          a = fmaf(q.x, t.x, a); a = fmaf(q.y, t.y, a);
          a = fmaf(q.z, t.z, a); a = fmaf(q.w, t.w, a);
          acc[ii][jj] = a;
        }
    }

    // online softmax (row groups of 16 lanes share a q-row)
#pragma unroll
    for (int ii = 0; ii < 4; ++ii) {
      float mx = fmaxf(fmaxf(acc[ii][0], acc[ii][1]),
                       fmaxf(acc[ii][2], acc[ii][3]));
      mx = fmaxf(mx, __shfl_xor(mx, 1));
      mx = fmaxf(mx, __shfl_xor(mx, 2));
      mx = fmaxf(mx, __shfl_xor(mx, 4));
      mx = fmaxf(mx, __shfl_xor(mx, 8));
      const float mnew = fmaxf(mrow[ii], mx);
      const float alpha = __expf(mrow[ii] - mnew);
      const float p0 = __expf(acc[ii][0] - mnew);
      const float p1 = __expf(acc[ii][1] - mnew);
      const float p2 = __expf(acc[ii][2] - mnew);
      const float p3 = __expf(acc[ii][3] - mnew);
      float ls = p0 + p1 + p2 + p3;
      ls += __shfl_xor(ls, 1);
      ls += __shfl_xor(ls, 2);
      ls += __shfl_xor(ls, 4);
      ls += __shfl_xor(ls, 8);
      lrow[ii] = lrow[ii] * alpha + ls;
      mrow[ii] = mnew;
      o[ii][0] *= alpha; o[ii][1] *= alpha;
      o[ii][2] *= alpha; o[ii][3] *= alpha;
      const float4 pv4 = {p0, p1, p2, p3};
      *(float4*)&ps[i0 + ii][j0] = pv4;
    }
    __syncthreads();

    // PV accumulate: o[i][d0..d0+3] += p[i][j] * v[j][d0..d0+3]
#pragma unroll 4
    for (int jb = 0; jb < 16; ++jb) {
      float pr[4][4];
      *(float4*)pr[0] = *(const float4*)&ps[i0 + 0][jb << 2];
      *(float4*)pr[1] = *(const float4*)&ps[i0 + 1][jb << 2];
      *(float4*)pr[2] = *(const float4*)&ps[i0 + 2][jb << 2];
      *(float4*)pr[3] = *(const float4*)&ps[i0 + 3][jb << 2];
#pragma unroll
      for (int jj = 0; jj < 4; ++jj) {
        const float4 vv = *(const float4*)&vs[(jb << 2) + jj][d0];
#pragma unroll
        for (int ii = 0; ii < 4; ++ii) {
          o[ii][0] = fmaf(pr[ii][jj], vv.x, o[ii][0]);
          o[ii][1] = fmaf(pr[ii][jj], vv.y, o[ii][1]);
          o[ii][2] = fmaf(pr[ii][jj], vv.z, o[ii][2]);
          o[ii][3] = fmaf(pr[ii][jj], vv.w, o[ii][3]);
        }
      }
    }
  }

  // write attention output: AO is [B, S, E] with e = h*64 + d
#pragma unroll
  for (int ii = 0; ii < 4; ++ii) {
    const float inv = 1.f / lrow[ii];
    const int s = s0 + i0 + ii;
    float4 v;
    v.x = o[ii][0] * inv; v.y = o[ii][1] * inv;
    v.z = o[ii][2] * inv; v.w = o[ii][3] * inv;
    *(float4*)(AO + ((size_t)b * S_LEN + s) * E_DIM + h * HD + d0) = v;
  }
}

// ---------------------------------------------------------------------------
extern "C" void kernel_launch(void* const* d_in, const int* in_sizes, int n_in,
                              void* d_out, int out_size, void* d_ws, size_t ws_size,
                              hipStream_t stream) {
  (void)in_sizes; (void)n_in; (void)out_size; (void)ws_size;
  const float* query = (const float*)d_in[0];
  const float* key   = (const float*)d_in[1];
  const float* value = (const float*)d_in[2];
  const float* Wq = (const float*)d_in[3];
  const float* bq = (const float*)d_in[4];
  const float* Wk = (const float*)d_in[5];
  const float* bk = (const float*)d_in[6];
  const float* Wv = (const float*)d_in[7];
  const float* bv = (const float*)d_in[8];
  const float* Wo = (const float*)d_in[9];
  const float* bo = (const float*)d_in[10];
  const float* tbl = (const float*)d_in[11];

  const size_t per = (size_t)B_SZ * H_NUM * S_LEN * HD;  // 4,194,304 floats
  float* wsQ = (float*)d_ws;
  float* wsK = wsQ + per;
  float* wsV = wsK + per;
  float* wsA = wsV + per;
  float* out = (float*)d_out;

  dim3 g(32, 8), blk(256);
  hipLaunchKernelGGL(proj_gemm, g, blk, 0, stream, query, Wq, bq, wsQ, 0.125f, 0);
  hipLaunchKernelGGL(proj_gemm, g, blk, 0, stream, key,   Wk, bk, wsK, 1.0f, 0);
  hipLaunchKernelGGL(proj_gemm, g, blk, 0, stream, value, Wv, bv, wsV, 1.0f, 0);
  hipLaunchKernelGGL(attn_rel, dim3(1024), blk, 0, stream, wsQ, wsK, wsV, tbl, wsA);
  hipLaunchKernelGGL(proj_gemm, g, blk, 0, stream, wsA, Wo, bo, out, 1.0f, 1);
}

// Round 2
// 647.041 us; speedup vs baseline: 1.7657x; 1.7657x over previous
//
#include <hip/hip_runtime.h>
#include <math.h>

#define S_LEN 1024
#define B_SZ 4
#define E_DIM 1024
#define H_NUM 16
#define HD 64
#define IDX_MAX 2044   // clip(dist,-1022,1022)+1022 in [0,2044]
#define NEG_BIG (-3.0e38f)

typedef __attribute__((ext_vector_type(8))) short s16x8;   // 8 bf16 (4 VGPRs)
typedef __attribute__((ext_vector_type(4))) float f32x4;

__device__ __forceinline__ unsigned short f2bf(float f) {
  union { float f; unsigned int u; } v; v.f = f;
  return (unsigned short)((v.u + 0x7FFFu + ((v.u >> 16) & 1u)) >> 16);  // RNE
}

// ---------------------------------------------------------------------------
// C = X[4096x1024] @ W^T + bias, fp32 compute, tile 128x128, 8x8 per thread.
// mode 0: X rows (s*B+b); out -> bf16 [B,H,S,hd] * scale
// mode 1: X rows (b*S+s); out -> fp32 [S,B,E]
// ---------------------------------------------------------------------------
__global__ __launch_bounds__(256) void proj_gemm(
    const float* __restrict__ X, const float* __restrict__ W,
    const float* __restrict__ bias, void* __restrict__ outp,
    float scale, int mode)
{
  __shared__ float Xs[16][132];
  __shared__ float Ws[16][132];

  const int tid = threadIdx.x;
  const int m0 = blockIdx.x << 7;
  const int n0 = blockIdx.y << 7;
  const int tr = tid >> 4;
  const int tc = tid & 15;

  float acc[8][8];
#pragma unroll
  for (int i = 0; i < 8; ++i)
#pragma unroll
    for (int j = 0; j < 8; ++j) acc[i][j] = 0.f;

  const int ldRow = tid >> 2;
  const int ldK   = (tid & 3) << 2;

  const float* Xp = X + (size_t)(m0 + ldRow) * E_DIM + ldK;
  const float* Wp = W + (size_t)(n0 + ldRow) * E_DIM + ldK;

  for (int kb = 0; kb < 64; ++kb) {
    const int k0 = kb << 4;
    const float4 xa = *(const float4*)(Xp + k0);
    const float4 xb = *(const float4*)(Xp + k0 + (size_t)64 * E_DIM);
    const float4 wa = *(const float4*)(Wp + k0);
    const float4 wb = *(const float4*)(Wp + k0 + (size_t)64 * E_DIM);
    __syncthreads();
    Xs[ldK + 0][ldRow] = xa.x; Xs[ldK + 1][ldRow] = xa.y;
    Xs[ldK + 2][ldRow] = xa.z; Xs[ldK + 3][ldRow] = xa.w;
    Xs[ldK + 0][ldRow + 64] = xb.x; Xs[ldK + 1][ldRow + 64] = xb.y;
    Xs[ldK + 2][ldRow + 64] = xb.z; Xs[ldK + 3][ldRow + 64] = xb.w;
    Ws[ldK + 0][ldRow] = wa.x; Ws[ldK + 1][ldRow] = wa.y;
    Ws[ldK + 2][ldRow] = wa.z; Ws[ldK + 3][ldRow] = wa.w;
    Ws[ldK + 0][ldRow + 64] = wb.x; Ws[ldK + 1][ldRow + 64] = wb.y;
    Ws[ldK + 2][ldRow + 64] = wb.z; Ws[ldK + 3][ldRow + 64] = wb.w;
    __syncthreads();
#pragma unroll
    for (int kk = 0; kk < 16; ++kk) {
      const float4 x0 = *(const float4*)&Xs[kk][tr << 2];
      const float4 x1 = *(const float4*)&Xs[kk][(tr << 2) + 64];
      const float4 w0 = *(const float4*)&Ws[kk][tc << 2];
      const float4 w1 = *(const float4*)&Ws[kk][(tc << 2) + 64];
      const float xr[8] = {x0.x, x0.y, x0.z, x0.w, x1.x, x1.y, x1.z, x1.w};
      const float wr[8] = {w0.x, w0.y, w0.z, w0.w, w1.x, w1.y, w1.z, w1.w};
#pragma unroll
      for (int i = 0; i < 8; ++i)
#pragma unroll
        for (int j = 0; j < 8; ++j)
          acc[i][j] = fmaf(xr[i], wr[j], acc[i][j]);
    }
  }

#pragma unroll
  for (int i = 0; i < 8; ++i) {
    const int m = m0 + (tr << 2) + (i & 3) + ((i >> 2) << 6);
#pragma unroll
    for (int jh = 0; jh < 2; ++jh) {
      const int n = n0 + (tc << 2) + (jh << 6);
      const float4 bv = *(const float4*)(bias + n);
      float4 v;
      v.x = (acc[i][jh * 4 + 0] + bv.x) * scale;
      v.y = (acc[i][jh * 4 + 1] + bv.y) * scale;
      v.z = (acc[i][jh * 4 + 2] + bv.z) * scale;
      v.w = (acc[i][jh * 4 + 3] + bv.w) * scale;
      if (mode == 0) {
        const int s = m >> 2, b2 = m & 3;
        const int h2 = n >> 6, d2 = n & 63;
        const size_t off = ((((size_t)b2 * H_NUM + h2) * S_LEN) + s) * HD + d2;
        unsigned int lo = (unsigned int)f2bf(v.x) | ((unsigned int)f2bf(v.y) << 16);
        unsigned int hi = (unsigned int)f2bf(v.z) | ((unsigned int)f2bf(v.w) << 16);
        unsigned int* dst = (unsigned int*)((unsigned short*)outp + off);
        dst[0] = lo; dst[1] = hi;
      } else {
        const int b2 = m >> 10, s = m & 1023;
        const size_t off = ((size_t)s * B_SZ + b2) * E_DIM + n;
        *(float4*)((float*)outp + off) = v;
      }
    }
  }
}

// ---------------------------------------------------------------------------
__global__ void conv_tbl(const float* __restrict__ in,
                         unsigned short* __restrict__ out, int n) {
  const int i = blockIdx.x * blockDim.x + threadIdx.x;
  if (i < n) out[i] = f2bf(in[i]);
}

// ---------------------------------------------------------------------------
// bf16 MFMA flash attention with relative-position band GEMM.
// Block: one (b,h) x 64 q-rows, 4 waves (16 rows each). t-tiles of 64.
// score = Q@K^T + gather(Q@RelBand^T). All LDS tiles chunk-XOR swizzled.
// ---------------------------------------------------------------------------
__global__ __launch_bounds__(256) void attn_mfma(
    const unsigned short* __restrict__ Qb, const unsigned short* __restrict__ Kb,
    const unsigned short* __restrict__ Vb, const unsigned short* __restrict__ Rb,
    float* __restrict__ AO)
{
  __shared__ unsigned short Ks[64 * 64];   // [j][d] swizzled
  __shared__ unsigned short Rs[128 * 64];  // [r][d] swizzled
  __shared__ unsigned short Vt[64 * 64];   // [d][j] swizzled (transposed)
  __shared__ unsigned short Ps[64 * 64];   // [i][j] swizzled
  __shared__ float band[64 * 132];         // [i][r] fp32, padded

  const int tid = threadIdx.x;
  const int lane = tid & 63;
  const int w = tid >> 6;
  const int st = blockIdx.x & 15;
  const int bh = blockIdx.x >> 4;
  const int s0 = st << 6;
  const int bb = bh >> 4;
  const int hh = bh & 15;
  const size_t base = (size_t)bh * (S_LEN * HD);

  const int l15 = lane & 15;
  const int l4 = lane >> 4;
  const int rb_ = w << 4;          // wave's q-row base within tile

  // Q fragments live in registers for the whole kernel (A-operand layout:
  // row = lane&15, k = (lane>>4)*8 + e, two K=32 halves)
  s16x8 qf0, qf1;
  {
    const unsigned short* qp =
        Qb + base + (size_t)(s0 + rb_ + l15) * HD + (l4 << 3);
    qf0 = *(const s16x8*)(qp);
    qf1 = *(const s16x8*)(qp + 32);
  }

  f32x4 of[4];
  float mrow[4], lrow[4];
#pragma unroll
  for (int m = 0; m < 4; ++m) {
    of[m] = (f32x4){0.f, 0.f, 0.f, 0.f};
    mrow[m] = NEG_BIG; lrow[m] = 0.f;
  }

  const int rbase = 959 - s0;   // + t0 + r -> global rel row (pre-clip)

  for (int tt = 0; tt < 16; ++tt) {
    const int t0 = tt << 6;
    __syncthreads();   // previous iteration's LDS reads done

    // ---- stage K tile (64x64 bf16): 512 16B chunks, 2/thread
#pragma unroll
    for (int v = 0; v < 2; ++v) {
      const int cid = tid + (v << 8);
      const int r = cid >> 3, cb = cid & 7;
      const s16x8 dv =
          *(const s16x8*)(Kb + base + (size_t)(t0 + r) * HD + (cb << 3));
      *(s16x8*)&Ks[(r << 6) + ((cb ^ (r & 7)) << 3)] = dv;
    }
    // ---- stage rel band (128x64 bf16): 1024 chunks, 4/thread
#pragma unroll
    for (int v = 0; v < 4; ++v) {
      const int cid = tid + (v << 8);
      const int r = cid >> 3, cb = cid & 7;
      int g = rbase + t0 + r;
      g = g < 0 ? 0 : (g > IDX_MAX ? IDX_MAX : g);
      const s16x8 dv = *(const s16x8*)(Rb + (size_t)g * HD + (cb << 3));
      *(s16x8*)&Rs[(r << 6) + ((cb ^ (r & 7)) << 3)] = dv;
    }
    // ---- stage V transposed: thread reads 2 rows x 8 cols, writes b32 pairs
    {
      const int jp = tid >> 3;          // 0..31 -> rows 2jp, 2jp+1
      const int c = tid & 7;            // d-chunk
      const unsigned short* vp =
          Vb + base + (size_t)(t0 + (jp << 1)) * HD + (c << 3);
      const s16x8 r0 = *(const s16x8*)(vp);
      const s16x8 r1 = *(const s16x8*)(vp + HD);
      const int jc = jp >> 2;
      const int jlow = (jp & 3) << 1;
#pragma unroll
      for (int e = 0; e < 8; ++e) {
        const int dd = (c << 3) + e;
        const unsigned int pack = (unsigned int)(unsigned short)r0[e] |
                                  ((unsigned int)(unsigned short)r1[e] << 16);
        *(unsigned int*)&Vt[(dd << 6) + ((jc ^ (dd & 7)) << 3) + jlow] = pack;
      }
    }
    __syncthreads();

    // ---- content (4 tiles) + band (8 tiles) MFMAs
    f32x4 cf[4], bf[8];
#pragma unroll
    for (int jt = 0; jt < 4; ++jt) cf[jt] = (f32x4){0.f, 0.f, 0.f, 0.f};
#pragma unroll
    for (int rt = 0; rt < 8; ++rt) bf[rt] = (f32x4){0.f, 0.f, 0.f, 0.f};

#pragma unroll
    for (int kk = 0; kk < 2; ++kk) {
      const s16x8 qv = kk ? qf1 : qf0;
      const int cb = l4 + (kk << 2);
#pragma unroll
      for (int jt = 0; jt < 4; ++jt) {
        const int r = (jt << 4) + l15;
        const s16x8 kf = *(const s16x8*)&Ks[(r << 6) + ((cb ^ (r & 7)) << 3)];
        cf[jt] = __builtin_amdgcn_mfma_f32_16x16x32_bf16(qv, kf, cf[jt], 0, 0, 0);
      }
#pragma unroll
      for (int rt = 0; rt < 8; ++rt) {
        const int r = (rt << 4) + l15;
        const s16x8 rf = *(const s16x8*)&Rs[(r << 6) + ((cb ^ (r & 7)) << 3)];
        bf[rt] = __builtin_amdgcn_mfma_f32_16x16x32_bf16(qv, rf, bf[rt], 0, 0, 0);
      }
    }

    // ---- band frags -> LDS (own rows only: no barrier, same-wave RAW)
#pragma unroll
    for (int rt = 0; rt < 8; ++rt)
#pragma unroll
      for (int m = 0; m < 4; ++m)
        band[(rb_ + (l4 << 2) + m) * 132 + (rt << 4) + l15] = bf[rt][m];

    // ---- softmax (online), P -> LDS bf16 (own rows)
#pragma unroll
    for (int m = 0; m < 4; ++m) {
      const int irow = rb_ + (l4 << 2) + m;
      const float* bp = &band[irow * 132 + 63 - irow];
      float sv[4];
      sv[0] = cf[0][m] + bp[l15];
      sv[1] = cf[1][m] + bp[16 + l15];
      sv[2] = cf[2][m] + bp[32 + l15];
      sv[3] = cf[3][m] + bp[48 + l15];
      float mx = fmaxf(fmaxf(sv[0], sv[1]), fmaxf(sv[2], sv[3]));
      mx = fmaxf(mx, __shfl_xor(mx, 1));
      mx = fmaxf(mx, __shfl_xor(mx, 2));
      mx = fmaxf(mx, __shfl_xor(mx, 4));
      mx = fmaxf(mx, __shfl_xor(mx, 8));
      const float mnew = fmaxf(mrow[m], mx);
      const float alpha = __expf(mrow[m] - mnew);
      float p[4], ls = 0.f;
#pragma unroll
      for (int jt = 0; jt < 4; ++jt) { p[jt] = __expf(sv[jt] - mnew); ls += p[jt]; }
      ls += __shfl_xor(ls, 1); ls += __shfl_xor(ls, 2);
      ls += __shfl_xor(ls, 4); ls += __shfl_xor(ls, 8);
      lrow[m] = lrow[m] * alpha + ls;
      mrow[m] = mnew;
#pragma unroll
      for (int dt = 0; dt < 4; ++dt) of[dt][m] *= alpha;
#pragma unroll
      for (int jt = 0; jt < 4; ++jt) {
        const int col = (jt << 4) + l15;
        const int ch = col >> 3;
        Ps[(irow << 6) + ((ch ^ (irow & 7)) << 3) + (col & 7)] = f2bf(p[jt]);
      }
    }

    // ---- PV: O[16x64] += P[16x64] @ V[64x64]  (A=P own rows, B=Vt)
#pragma unroll
    for (int kk = 0; kk < 2; ++kk) {
      const int cb = l4 + (kk << 2);
      const int pr = rb_ + l15;
      const s16x8 pf = *(const s16x8*)&Ps[(pr << 6) + ((cb ^ (pr & 7)) << 3)];
#pragma unroll
      for (int dt = 0; dt < 4; ++dt) {
        const int dr = (dt << 4) + l15;
        const s16x8 vf = *(const s16x8*)&Vt[(dr << 6) + ((cb ^ (dr & 7)) << 3)];
        of[dt] = __builtin_amdgcn_mfma_f32_16x16x32_bf16(pf, vf, of[dt], 0, 0, 0);
      }
    }
  }

  // ---- epilogue: normalize, write AO fp32 [B,S,E] at e = h*64 + d
#pragma unroll
  for (int m = 0; m < 4; ++m) {
    const float inv = 1.f / lrow[m];
    const int srow = s0 + rb_ + (l4 << 2) + m;
    float* op = AO + ((size_t)bb * S_LEN + srow) * E_DIM + (hh << 6) + l15;
#pragma unroll
    for (int dt = 0; dt < 4; ++dt)
      op[dt << 4] = of[dt][m] * inv;
  }
}

// ---------------------------------------------------------------------------
extern "C" void kernel_launch(void* const* d_in, const int* in_sizes, int n_in,
                              void* d_out, int out_size, void* d_ws, size_t ws_size,
                              hipStream_t stream) {
  (void)in_sizes; (void)n_in; (void)out_size; (void)ws_size;
  const float* query = (const float*)d_in[0];
  const float* key   = (const float*)d_in[1];
  const float* value = (const float*)d_in[2];
  const float* Wq = (const float*)d_in[3];
  const float* bq = (const float*)d_in[4];
  const float* Wk = (const float*)d_in[5];
  const float* bk = (const float*)d_in[6];
  const float* Wv = (const float*)d_in[7];
  const float* bv = (const float*)d_in[8];
  const float* Wo = (const float*)d_in[9];
  const float* bo = (const float*)d_in[10];
  const float* tbl = (const float*)d_in[11];

  const size_t per = (size_t)B_SZ * H_NUM * S_LEN * HD;  // 4,194,304 elems
  unsigned short* wsQb = (unsigned short*)d_ws;
  unsigned short* wsKb = wsQb + per;
  unsigned short* wsVb = wsKb + per;
  unsigned short* wsRb = wsVb + per;            // 131008 used, 131072 reserved
  float* wsA = (float*)(wsRb + 131072);         // fp32 [B,S,E]
  float* out = (float*)d_out;

  dim3 g(32, 8), blk(256);
  hipLaunchKernelGGL(conv_tbl, dim3(512), blk, 0, stream, tbl, wsRb, 2047 * 64);
  hipLaunchKernelGGL(proj_gemm, g, blk, 0, stream, query, Wq, bq, (void*)wsQb, 0.125f, 0);
  hipLaunchKernelGGL(proj_gemm, g, blk, 0, stream, key,   Wk, bk, (void*)wsKb, 1.0f, 0);
  hipLaunchKernelGGL(proj_gemm, g, blk, 0, stream, value, Wv, bv, (void*)wsVb, 1.0f, 0);
  hipLaunchKernelGGL(attn_mfma, dim3(1024), blk, 0, stream, wsQb, wsKb, wsVb, wsRb, wsA);
  hipLaunchKernelGGL(proj_gemm, g, blk, 0, stream, wsA, Wo, bo, (void*)out, 1.0f, 1);
}

// Round 3
// 206.112 us; speedup vs baseline: 5.5431x; 3.1393x over previous
//
#include <hip/hip_runtime.h>
#include <math.h>

#define S_LEN 1024
#define B_SZ 4
#define E_DIM 1024
#define H_NUM 16
#define HD 64
#define IDX_MAX 2044   // clip(dist,-1022,1022)+1022 in [0,2044]
#define NEG_BIG (-3.0e38f)

typedef __attribute__((ext_vector_type(8))) short s16x8;   // 8 bf16 (4 VGPRs)
typedef __attribute__((ext_vector_type(4))) float f32x4;

__device__ __forceinline__ unsigned short f2bf(float f) {
  union { float f; unsigned int u; } v; v.f = f;
  return (unsigned short)((v.u + 0x7FFFu + ((v.u >> 16) & 1u)) >> 16);  // RNE
}
__device__ __forceinline__ float bf2f(unsigned short h) {
  union { unsigned int u; float f; } v; v.u = ((unsigned int)h) << 16;
  return v.f;
}
__device__ __forceinline__ void gload16(const void* g, void* l) {
  __builtin_amdgcn_global_load_lds(
      (const __attribute__((address_space(1))) void*)g,
      (__attribute__((address_space(3))) void*)l, 16, 0, 0);
}

// ---------------------------------------------------------------------------
// fp32 -> bf16 elementwise (n % 8 == 0 for all our tensors)
// ---------------------------------------------------------------------------
__global__ __launch_bounds__(256) void conv_bf16(
    const float* __restrict__ in, unsigned short* __restrict__ out, int n) {
  const int i = (blockIdx.x * 256 + threadIdx.x) << 3;
  if (i >= n) return;
  const float4 a = *(const float4*)(in + i);
  const float4 b = *(const float4*)(in + i + 4);
  union { unsigned short us[8]; uint4 v; } u;
  u.us[0] = f2bf(a.x); u.us[1] = f2bf(a.y); u.us[2] = f2bf(a.z); u.us[3] = f2bf(a.w);
  u.us[4] = f2bf(b.x); u.us[5] = f2bf(b.y); u.us[6] = f2bf(b.z); u.us[7] = f2bf(b.w);
  *(uint4*)(out + i) = u.v;
}

// ---------------------------------------------------------------------------
// Fused QKV projection: C[m][n] = X[m]·W[n] (+bias)*scale, bf16 MFMA.
// M=4096 (rows s*B+b), N=1024, K=1024. Tile 128x128, BK=64, 4 waves 2x2.
// Epilogue -> bf16 [B,H,S,hd].  z selects q/k/v.
// ---------------------------------------------------------------------------
__global__ __launch_bounds__(256, 3) void qkv_mfma(
    const unsigned short* __restrict__ X0, const unsigned short* __restrict__ X1,
    const unsigned short* __restrict__ X2,
    const unsigned short* __restrict__ W0, const unsigned short* __restrict__ W1,
    const unsigned short* __restrict__ W2,
    const float* __restrict__ bp0, const float* __restrict__ bp1,
    const float* __restrict__ bp2,
    unsigned short* __restrict__ O0, unsigned short* __restrict__ O1,
    unsigned short* __restrict__ O2)
{
  __shared__ unsigned short As[128 * 64];
  __shared__ unsigned short Bs[128 * 64];

  const int z = blockIdx.z;
  const unsigned short* X = z == 0 ? X0 : (z == 1 ? X1 : X2);
  const unsigned short* W = z == 0 ? W0 : (z == 1 ? W1 : W2);
  const float* bias = z == 0 ? bp0 : (z == 1 ? bp1 : bp2);
  unsigned short* O = z == 0 ? O0 : (z == 1 ? O1 : O2);
  const float scale = z == 0 ? 0.125f : 1.0f;

  const int tid = threadIdx.x;
  const int w = tid >> 6, l = tid & 63;
  const int l15 = l & 15, l4 = l >> 4;
  const int m0 = blockIdx.x << 7, n0 = blockIdx.y << 7;
  const int wr0 = (w >> 1) << 6, wc0 = (w & 1) << 6;

  f32x4 acc[4][4];
#pragma unroll
  for (int mt = 0; mt < 4; ++mt)
#pragma unroll
    for (int nt = 0; nt < 4; ++nt) acc[mt][nt] = (f32x4){0.f, 0.f, 0.f, 0.f};

  float bias4[4];
#pragma unroll
  for (int nt = 0; nt < 4; ++nt) bias4[nt] = bias[n0 + wc0 + (nt << 4) + l15];

  const int cbase = (w << 6) + l;   // + i*256 -> chunk id (16B chunks)

  for (int kt = 0; kt < 16; ++kt) {
    const int k0 = kt << 6;
    __syncthreads();   // previous compute's LDS reads done
#pragma unroll
    for (int i = 0; i < 4; ++i) {
      const int c = cbase + (i << 8);
      const int r = c >> 3, kc = c & 7;          // tile row, 16B chunk in row
      char* ldsA = (char*)As + (((i << 2) + w) << 10);
      char* ldsB = (char*)Bs + (((i << 2) + w) << 10);
      gload16(X + (size_t)(m0 + r) * E_DIM + k0 + (kc << 3), ldsA);
      gload16(W + (size_t)(n0 + r) * E_DIM + k0 + (kc << 3), ldsB);
    }
    __syncthreads();   // compiler drains vmcnt before barrier
#pragma unroll
    for (int kh = 0; kh < 2; ++kh) {
      s16x8 af[4], bfr[4];
#pragma unroll
      for (int mt = 0; mt < 4; ++mt)
        af[mt] = *(const s16x8*)&As[(wr0 + (mt << 4) + l15) * 64 + (kh << 5) + (l4 << 3)];
#pragma unroll
      for (int nt = 0; nt < 4; ++nt)
        bfr[nt] = *(const s16x8*)&Bs[(wc0 + (nt << 4) + l15) * 64 + (kh << 5) + (l4 << 3)];
#pragma unroll
      for (int mt = 0; mt < 4; ++mt)
#pragma unroll
        for (int nt = 0; nt < 4; ++nt)
          acc[mt][nt] = __builtin_amdgcn_mfma_f32_16x16x32_bf16(
              af[mt], bfr[nt], acc[mt][nt], 0, 0, 0);
    }
  }

  // epilogue: C row m=(s*4+b), col n=(h*64+d) -> O[b][h][s][d] bf16
#pragma unroll
  for (int mt = 0; mt < 4; ++mt)
#pragma unroll
    for (int nt = 0; nt < 4; ++nt) {
      const int n = n0 + wc0 + (nt << 4) + l15;
      const int h = n >> 6, d = n & 63;
      const f32x4 c = acc[mt][nt];
#pragma unroll
      for (int r = 0; r < 4; ++r) {
        const int m = m0 + wr0 + (mt << 4) + (l4 << 2) + r;
        const int s = m >> 2, b = m & 3;
        O[((((size_t)b * H_NUM + h) * S_LEN) + s) * HD + d] =
            f2bf((c[r] + bias4[nt]) * scale);
      }
    }
}

// ---------------------------------------------------------------------------
// Output projection with hi/lo split A (2-pass MFMA ~ fp32 accuracy).
// A rows m = b*1024+s ([B,S,E] bf16 hi+lo), out fp32 [S,B,E].
// ---------------------------------------------------------------------------
__global__ __launch_bounds__(256) void outp_mfma(
    const unsigned short* __restrict__ Ah, const unsigned short* __restrict__ Al,
    const unsigned short* __restrict__ W, const float* __restrict__ bias,
    float* __restrict__ out)
{
  __shared__ unsigned short Ahs[128 * 64];
  __shared__ unsigned short Als[128 * 64];
  __shared__ unsigned short Bs[128 * 64];

  const int tid = threadIdx.x;
  const int w = tid >> 6, l = tid & 63;
  const int l15 = l & 15, l4 = l >> 4;
  const int m0 = blockIdx.x << 7, n0 = blockIdx.y << 7;
  const int wr0 = (w >> 1) << 6, wc0 = (w & 1) << 6;

  f32x4 acc[4][4];
#pragma unroll
  for (int mt = 0; mt < 4; ++mt)
#pragma unroll
    for (int nt = 0; nt < 4; ++nt) acc[mt][nt] = (f32x4){0.f, 0.f, 0.f, 0.f};

  float bias4[4];
#pragma unroll
  for (int nt = 0; nt < 4; ++nt) bias4[nt] = bias[n0 + wc0 + (nt << 4) + l15];

  const int cbase = (w << 6) + l;

  for (int kt = 0; kt < 16; ++kt) {
    const int k0 = kt << 6;
    __syncthreads();
#pragma unroll
    for (int i = 0; i < 4; ++i) {
      const int c = cbase + (i << 8);
      const int r = c >> 3, kc = c & 7;
      char* ldsAh = (char*)Ahs + (((i << 2) + w) << 10);
      char* ldsAl = (char*)Als + (((i << 2) + w) << 10);
      char* ldsB  = (char*)Bs  + (((i << 2) + w) << 10);
      gload16(Ah + (size_t)(m0 + r) * E_DIM + k0 + (kc << 3), ldsAh);
      gload16(Al + (size_t)(m0 + r) * E_DIM + k0 + (kc << 3), ldsAl);
      gload16(W  + (size_t)(n0 + r) * E_DIM + k0 + (kc << 3), ldsB);
    }
    __syncthreads();
#pragma unroll
    for (int kh = 0; kh < 2; ++kh) {
      s16x8 ah[4], al[4], bfr[4];
      const int ko = (kh << 5) + (l4 << 3);
#pragma unroll
      for (int mt = 0; mt < 4; ++mt) {
        ah[mt] = *(const s16x8*)&Ahs[(wr0 + (mt << 4) + l15) * 64 + ko];
        al[mt] = *(const s16x8*)&Als[(wr0 + (mt << 4) + l15) * 64 + ko];
      }
#pragma unroll
      for (int nt = 0; nt < 4; ++nt)
        bfr[nt] = *(const s16x8*)&Bs[(wc0 + (nt << 4) + l15) * 64 + ko];
#pragma unroll
      for (int mt = 0; mt < 4; ++mt)
#pragma unroll
        for (int nt = 0; nt < 4; ++nt) {
          acc[mt][nt] = __builtin_amdgcn_mfma_f32_16x16x32_bf16(
              ah[mt], bfr[nt], acc[mt][nt], 0, 0, 0);
          acc[mt][nt] = __builtin_amdgcn_mfma_f32_16x16x32_bf16(
              al[mt], bfr[nt], acc[mt][nt], 0, 0, 0);
        }
    }
  }

  // epilogue: A row m -> (b=m>>10, s=m&1023); out[s][b][n] fp32
#pragma unroll
  for (int mt = 0; mt < 4; ++mt)
#pragma unroll
    for (int nt = 0; nt < 4; ++nt) {
      const int n = n0 + wc0 + (nt << 4) + l15;
      const f32x4 c = acc[mt][nt];
#pragma unroll
      for (int r = 0; r < 4; ++r) {
        const int m = m0 + wr0 + (mt << 4) + (l4 << 2) + r;
        const int b = m >> 10, s = m & 1023;
        out[((size_t)s * B_SZ + b) * E_DIM + n] = c[r] + bias4[nt];
      }
    }
}

// ---------------------------------------------------------------------------
// bf16 MFMA flash attention with relative-position band GEMM (validated R2).
// Epilogue now emits hi/lo bf16 split of the output.
// ---------------------------------------------------------------------------
__global__ __launch_bounds__(256) void attn_mfma(
    const unsigned short* __restrict__ Qb, const unsigned short* __restrict__ Kb,
    const unsigned short* __restrict__ Vb, const unsigned short* __restrict__ Rb,
    unsigned short* __restrict__ AOh, unsigned short* __restrict__ AOl)
{
  __shared__ unsigned short Ks[64 * 64];   // [j][d] swizzled
  __shared__ unsigned short Rs[128 * 64];  // [r][d] swizzled
  __shared__ unsigned short Vt[64 * 64];   // [d][j] swizzled (transposed)
  __shared__ unsigned short Ps[64 * 64];   // [i][j] swizzled
  __shared__ float band[64 * 132];         // [i][r] fp32, padded

  const int tid = threadIdx.x;
  const int lane = tid & 63;
  const int w = tid >> 6;
  const int st = blockIdx.x & 15;
  const int bh = blockIdx.x >> 4;
  const int s0 = st << 6;
  const int bb = bh >> 4;
  const int hh = bh & 15;
  const size_t base = (size_t)bh * (S_LEN * HD);

  const int l15 = lane & 15;
  const int l4 = lane >> 4;
  const int rb_ = w << 4;

  s16x8 qf0, qf1;
  {
    const unsigned short* qp =
        Qb + base + (size_t)(s0 + rb_ + l15) * HD + (l4 << 3);
    qf0 = *(const s16x8*)(qp);
    qf1 = *(const s16x8*)(qp + 32);
  }

  f32x4 of[4];
  float mrow[4], lrow[4];
#pragma unroll
  for (int m = 0; m < 4; ++m) {
    of[m] = (f32x4){0.f, 0.f, 0.f, 0.f};
    mrow[m] = NEG_BIG; lrow[m] = 0.f;
  }

  const int rbase = 959 - s0;

  for (int tt = 0; tt < 16; ++tt) {
    const int t0 = tt << 6;
    __syncthreads();

#pragma unroll
    for (int v = 0; v < 2; ++v) {
      const int cid = tid + (v << 8);
      const int r = cid >> 3, cb = cid & 7;
      const s16x8 dv =
          *(const s16x8*)(Kb + base + (size_t)(t0 + r) * HD + (cb << 3));
      *(s16x8*)&Ks[(r << 6) + ((cb ^ (r & 7)) << 3)] = dv;
    }
#pragma unroll
    for (int v = 0; v < 4; ++v) {
      const int cid = tid + (v << 8);
      const int r = cid >> 3, cb = cid & 7;
      int g = rbase + t0 + r;
      g = g < 0 ? 0 : (g > IDX_MAX ? IDX_MAX : g);
      const s16x8 dv = *(const s16x8*)(Rb + (size_t)g * HD + (cb << 3));
      *(s16x8*)&Rs[(r << 6) + ((cb ^ (r & 7)) << 3)] = dv;
    }
    {
      const int jp = tid >> 3;
      const int c = tid & 7;
      const unsigned short* vp =
          Vb + base + (size_t)(t0 + (jp << 1)) * HD + (c << 3);
      const s16x8 r0 = *(const s16x8*)(vp);
      const s16x8 r1 = *(const s16x8*)(vp + HD);
      const int jc = jp >> 2;
      const int jlow = (jp & 3) << 1;
#pragma unroll
      for (int e = 0; e < 8; ++e) {
        const int dd = (c << 3) + e;
        const unsigned int pack = (unsigned int)(unsigned short)r0[e] |
                                  ((unsigned int)(unsigned short)r1[e] << 16);
        *(unsigned int*)&Vt[(dd << 6) + ((jc ^ (dd & 7)) << 3) + jlow] = pack;
      }
    }
    __syncthreads();

    f32x4 cf[4], bfq[8];
#pragma unroll
    for (int jt = 0; jt < 4; ++jt) cf[jt] = (f32x4){0.f, 0.f, 0.f, 0.f};
#pragma unroll
    for (int rt = 0; rt < 8; ++rt) bfq[rt] = (f32x4){0.f, 0.f, 0.f, 0.f};

#pragma unroll
    for (int kk = 0; kk < 2; ++kk) {
      const s16x8 qv = kk ? qf1 : qf0;
      const int cb = l4 + (kk << 2);
#pragma unroll
      for (int jt = 0; jt < 4; ++jt) {
        const int r = (jt << 4) + l15;
        const s16x8 kf = *(const s16x8*)&Ks[(r << 6) + ((cb ^ (r & 7)) << 3)];
        cf[jt] = __builtin_amdgcn_mfma_f32_16x16x32_bf16(qv, kf, cf[jt], 0, 0, 0);
      }
#pragma unroll
      for (int rt = 0; rt < 8; ++rt) {
        const int r = (rt << 4) + l15;
        const s16x8 rf = *(const s16x8*)&Rs[(r << 6) + ((cb ^ (r & 7)) << 3)];
        bfq[rt] = __builtin_amdgcn_mfma_f32_16x16x32_bf16(qv, rf, bfq[rt], 0, 0, 0);
      }
    }

#pragma unroll
    for (int rt = 0; rt < 8; ++rt)
#pragma unroll
      for (int m = 0; m < 4; ++m)
        band[(rb_ + (l4 << 2) + m) * 132 + (rt << 4) + l15] = bfq[rt][m];

#pragma unroll
    for (int m = 0; m < 4; ++m) {
      const int irow = rb_ + (l4 << 2) + m;
      const float* bp = &band[irow * 132 + 63 - irow];
      float sv[4];
      sv[0] = cf[0][m] + bp[l15];
      sv[1] = cf[1][m] + bp[16 + l15];
      sv[2] = cf[2][m] + bp[32 + l15];
      sv[3] = cf[3][m] + bp[48 + l15];
      float mx = fmaxf(fmaxf(sv[0], sv[1]), fmaxf(sv[2], sv[3]));
      mx = fmaxf(mx, __shfl_xor(mx, 1));
      mx = fmaxf(mx, __shfl_xor(mx, 2));
      mx = fmaxf(mx, __shfl_xor(mx, 4));
      mx = fmaxf(mx, __shfl_xor(mx, 8));
      const float mnew = fmaxf(mrow[m], mx);
      const float alpha = __expf(mrow[m] - mnew);
      float p[4], ls = 0.f;
#pragma unroll
      for (int jt = 0; jt < 4; ++jt) { p[jt] = __expf(sv[jt] - mnew); ls += p[jt]; }
      ls += __shfl_xor(ls, 1); ls += __shfl_xor(ls, 2);
      ls += __shfl_xor(ls, 4); ls += __shfl_xor(ls, 8);
      lrow[m] = lrow[m] * alpha + ls;
      mrow[m] = mnew;
#pragma unroll
      for (int dt = 0; dt < 4; ++dt) of[dt][m] *= alpha;
#pragma unroll
      for (int jt = 0; jt < 4; ++jt) {
        const int col = (jt << 4) + l15;
        const int ch = col >> 3;
        Ps[(irow << 6) + ((ch ^ (irow & 7)) << 3) + (col & 7)] = f2bf(p[jt]);
      }
    }

#pragma unroll
    for (int kk = 0; kk < 2; ++kk) {
      const int cb = l4 + (kk << 2);
      const int pr = rb_ + l15;
      const s16x8 pf = *(const s16x8*)&Ps[(pr << 6) + ((cb ^ (pr & 7)) << 3)];
#pragma unroll
      for (int dt = 0; dt < 4; ++dt) {
        const int dr = (dt << 4) + l15;
        const s16x8 vf = *(const s16x8*)&Vt[(dr << 6) + ((cb ^ (dr & 7)) << 3)];
        of[dt] = __builtin_amdgcn_mfma_f32_16x16x32_bf16(pf, vf, of[dt], 0, 0, 0);
      }
    }
  }

  // epilogue: hi/lo bf16 split of normalized output, [B,S,E] at e=h*64+d
#pragma unroll
  for (int m = 0; m < 4; ++m) {
    const float inv = 1.f / lrow[m];
    const int srow = s0 + rb_ + (l4 << 2) + m;
    const size_t off0 = ((size_t)bb * S_LEN + srow) * E_DIM + (hh << 6) + l15;
#pragma unroll
    for (int dt = 0; dt < 4; ++dt) {
      const float x = of[dt][m] * inv;
      const unsigned short hi = f2bf(x);
      AOh[off0 + (dt << 4)] = hi;
      AOl[off0 + (dt << 4)] = f2bf(x - bf2f(hi));
    }
  }
}

// ---------------------------------------------------------------------------
extern "C" void kernel_launch(void* const* d_in, const int* in_sizes, int n_in,
                              void* d_out, int out_size, void* d_ws, size_t ws_size,
                              hipStream_t stream) {
  (void)in_sizes; (void)n_in; (void)out_size; (void)ws_size;
  const float* query = (const float*)d_in[0];
  const float* key   = (const float*)d_in[1];
  const float* value = (const float*)d_in[2];
  const float* Wq = (const float*)d_in[3];
  const float* bq = (const float*)d_in[4];
  const float* Wk = (const float*)d_in[5];
  const float* bk = (const float*)d_in[6];
  const float* Wv = (const float*)d_in[7];
  const float* bv = (const float*)d_in[8];
  const float* Wo = (const float*)d_in[9];
  const float* bo = (const float*)d_in[10];
  const float* tbl = (const float*)d_in[11];

  const size_t per = (size_t)B_SZ * H_NUM * S_LEN * HD;   // 4,194,304 elems
  const size_t wsz = (size_t)E_DIM * E_DIM;               // 1,048,576 elems
  unsigned short* p = (unsigned short*)d_ws;
  unsigned short* wsQb = p; p += per;      // q [B,H,S,hd] bf16
  unsigned short* wsKb = p; p += per;
  unsigned short* wsVb = p; p += per;
  unsigned short* wsRb = p; p += 131072;   // rel table bf16
  unsigned short* wsXq = p; p += per;      // bf16 copies of inputs
  unsigned short* wsXk = p; p += per;
  unsigned short* wsXv = p; p += per;
  unsigned short* wsWq = p; p += wsz;      // bf16 weights
  unsigned short* wsWk = p; p += wsz;
  unsigned short* wsWv = p; p += wsz;
  unsigned short* wsWo = p; p += wsz;
  unsigned short* wsAh = p; p += per;      // attn out hi
  unsigned short* wsAl = p; p += per;      // attn out lo
  float* out = (float*)d_out;

  dim3 blk(256);
  const int nIn = (int)per, nW = (int)wsz;
  hipLaunchKernelGGL(conv_bf16, dim3(2048), blk, 0, stream, query, wsXq, nIn);
  hipLaunchKernelGGL(conv_bf16, dim3(2048), blk, 0, stream, key,   wsXk, nIn);
  hipLaunchKernelGGL(conv_bf16, dim3(2048), blk, 0, stream, value, wsXv, nIn);
  hipLaunchKernelGGL(conv_bf16, dim3(512), blk, 0, stream, Wq, wsWq, nW);
  hipLaunchKernelGGL(conv_bf16, dim3(512), blk, 0, stream, Wk, wsWk, nW);
  hipLaunchKernelGGL(conv_bf16, dim3(512), blk, 0, stream, Wv, wsWv, nW);
  hipLaunchKernelGGL(conv_bf16, dim3(512), blk, 0, stream, Wo, wsWo, nW);
  hipLaunchKernelGGL(conv_bf16, dim3(64), blk, 0, stream, tbl, wsRb, 2047 * 64);

  hipLaunchKernelGGL(qkv_mfma, dim3(32, 8, 3), blk, 0, stream,
                     wsXq, wsXk, wsXv, wsWq, wsWk, wsWv, bq, bk, bv,
                     wsQb, wsKb, wsVb);
  hipLaunchKernelGGL(attn_mfma, dim3(1024), blk, 0, stream,
                     wsQb, wsKb, wsVb, wsRb, wsAh, wsAl);
  hipLaunchKernelGGL(outp_mfma, dim3(32, 8), blk, 0, stream,
                     wsAh, wsAl, wsWo, bo, out);
}

// Round 4
// 180.750 us; speedup vs baseline: 6.3209x; 1.1403x over previous
//
#include <hip/hip_runtime.h>
#include <math.h>

#define S_LEN 1024
#define B_SZ 4
#define E_DIM 1024
#define H_NUM 16
#define HD 64
#define IDX_MAX 2044   // clip(dist,-1022,1022)+1022 in [0,2044]
#define NEG_BIG (-3.0e38f)

typedef __attribute__((ext_vector_type(8))) short s16x8;   // 8 bf16 (4 VGPRs)
typedef __attribute__((ext_vector_type(4))) float f32x4;

__device__ __forceinline__ unsigned short f2bf(float f) {
  union { float f; unsigned int u; } v; v.f = f;
  return (unsigned short)((v.u + 0x7FFFu + ((v.u >> 16) & 1u)) >> 16);  // RNE
}
__device__ __forceinline__ float bf2f(unsigned short h) {
  union { unsigned int u; float f; } v; v.u = ((unsigned int)h) << 16;
  return v.f;
}
__device__ __forceinline__ void gload16(const void* g, void* l) {
  __builtin_amdgcn_global_load_lds(
      (const __attribute__((address_space(1))) void*)g,
      (__attribute__((address_space(3))) void*)l, 16, 0, 0);
}
__device__ __forceinline__ int clampg(int g) {
  return g < 0 ? 0 : (g > IDX_MAX ? IDX_MAX : g);
}

// ---------------------------------------------------------------------------
// All fp32->bf16 conversions in one launch (8 segments).
// ---------------------------------------------------------------------------
__global__ __launch_bounds__(256) void conv_all(
    const float* __restrict__ q, const float* __restrict__ k,
    const float* __restrict__ v, const float* __restrict__ wq,
    const float* __restrict__ wk, const float* __restrict__ wv,
    const float* __restrict__ wo, const float* __restrict__ tb,
    unsigned short* __restrict__ oq, unsigned short* __restrict__ ok,
    unsigned short* __restrict__ ov, unsigned short* __restrict__ owq,
    unsigned short* __restrict__ owk, unsigned short* __restrict__ owv,
    unsigned short* __restrict__ owo, unsigned short* __restrict__ otb)
{
  const int b = blockIdx.x;
  const float* src; unsigned short* dst; int n, lb;
  if (b < 2048)      { src = q;  dst = oq;  n = 4194304; lb = b; }
  else if (b < 4096) { src = k;  dst = ok;  n = 4194304; lb = b - 2048; }
  else if (b < 6144) { src = v;  dst = ov;  n = 4194304; lb = b - 4096; }
  else if (b < 6656) { src = wq; dst = owq; n = 1048576; lb = b - 6144; }
  else if (b < 7168) { src = wk; dst = owk; n = 1048576; lb = b - 6656; }
  else if (b < 7680) { src = wv; dst = owv; n = 1048576; lb = b - 7168; }
  else if (b < 8192) { src = wo; dst = owo; n = 1048576; lb = b - 7680; }
  else               { src = tb; dst = otb; n = 131008;  lb = b - 8192; }
  const int i = (lb * 256 + threadIdx.x) << 3;
  if (i >= n) return;
  const float4 a = *(const float4*)(src + i);
  const float4 c = *(const float4*)(src + i + 4);
  union { unsigned short us[8]; uint4 v4; } u;
  u.us[0] = f2bf(a.x); u.us[1] = f2bf(a.y); u.us[2] = f2bf(a.z); u.us[3] = f2bf(a.w);
  u.us[4] = f2bf(c.x); u.us[5] = f2bf(c.y); u.us[6] = f2bf(c.z); u.us[7] = f2bf(c.w);
  *(uint4*)(dst + i) = u.v4;
}

// ---------------------------------------------------------------------------
// Fused QKV projection: C[m][n] = X[m]·W[n] (+bias)*scale, bf16 MFMA.
// M=4096 (rows s*B+b), N=1024, K=1024. Tile 128x128, BK=64, 4 waves 2x2.
// ---------------------------------------------------------------------------
__global__ __launch_bounds__(256, 3) void qkv_mfma(
    const unsigned short* __restrict__ X0, const unsigned short* __restrict__ X1,
    const unsigned short* __restrict__ X2,
    const unsigned short* __restrict__ W0, const unsigned short* __restrict__ W1,
    const unsigned short* __restrict__ W2,
    const float* __restrict__ bp0, const float* __restrict__ bp1,
    const float* __restrict__ bp2,
    unsigned short* __restrict__ O0, unsigned short* __restrict__ O1,
    unsigned short* __restrict__ O2)
{
  __shared__ unsigned short As[128 * 64];
  __shared__ unsigned short Bs[128 * 64];

  const int z = blockIdx.z;
  const unsigned short* X = z == 0 ? X0 : (z == 1 ? X1 : X2);
  const unsigned short* W = z == 0 ? W0 : (z == 1 ? W1 : W2);
  const float* bias = z == 0 ? bp0 : (z == 1 ? bp1 : bp2);
  unsigned short* O = z == 0 ? O0 : (z == 1 ? O1 : O2);
  const float scale = z == 0 ? 0.125f : 1.0f;

  const int tid = threadIdx.x;
  const int w = tid >> 6, l = tid & 63;
  const int l15 = l & 15, l4 = l >> 4;
  const int m0 = blockIdx.x << 7, n0 = blockIdx.y << 7;
  const int wr0 = (w >> 1) << 6, wc0 = (w & 1) << 6;

  f32x4 acc[4][4];
#pragma unroll
  for (int mt = 0; mt < 4; ++mt)
#pragma unroll
    for (int nt = 0; nt < 4; ++nt) acc[mt][nt] = (f32x4){0.f, 0.f, 0.f, 0.f};

  float bias4[4];
#pragma unroll
  for (int nt = 0; nt < 4; ++nt) bias4[nt] = bias[n0 + wc0 + (nt << 4) + l15];

  const int cbase = (w << 6) + l;

  for (int kt = 0; kt < 16; ++kt) {
    const int k0 = kt << 6;
    __syncthreads();
#pragma unroll
    for (int i = 0; i < 4; ++i) {
      const int c = cbase + (i << 8);
      const int r = c >> 3, kc = c & 7;
      char* ldsA = (char*)As + (((i << 2) + w) << 10);
      char* ldsB = (char*)Bs + (((i << 2) + w) << 10);
      gload16(X + (size_t)(m0 + r) * E_DIM + k0 + (kc << 3), ldsA);
      gload16(W + (size_t)(n0 + r) * E_DIM + k0 + (kc << 3), ldsB);
    }
    __syncthreads();
#pragma unroll
    for (int kh = 0; kh < 2; ++kh) {
      s16x8 af[4], bfr[4];
#pragma unroll
      for (int mt = 0; mt < 4; ++mt)
        af[mt] = *(const s16x8*)&As[(wr0 + (mt << 4) + l15) * 64 + (kh << 5) + (l4 << 3)];
#pragma unroll
      for (int nt = 0; nt < 4; ++nt)
        bfr[nt] = *(const s16x8*)&Bs[(wc0 + (nt << 4) + l15) * 64 + (kh << 5) + (l4 << 3)];
#pragma unroll
      for (int mt = 0; mt < 4; ++mt)
#pragma unroll
        for (int nt = 0; nt < 4; ++nt)
          acc[mt][nt] = __builtin_amdgcn_mfma_f32_16x16x32_bf16(
              af[mt], bfr[nt], acc[mt][nt], 0, 0, 0);
    }
  }

#pragma unroll
  for (int mt = 0; mt < 4; ++mt)
#pragma unroll
    for (int nt = 0; nt < 4; ++nt) {
      const int n = n0 + wc0 + (nt << 4) + l15;
      const int h = n >> 6, d = n & 63;
      const f32x4 c = acc[mt][nt];
#pragma unroll
      for (int r = 0; r < 4; ++r) {
        const int m = m0 + wr0 + (mt << 4) + (l4 << 2) + r;
        const int s = m >> 2, b = m & 3;
        O[((((size_t)b * H_NUM + h) * S_LEN) + s) * HD + d] =
            f2bf((c[r] + bias4[nt]) * scale);
      }
    }
}

// ---------------------------------------------------------------------------
// Output projection with hi/lo split A (2-pass MFMA ~ fp32 accuracy).
// ---------------------------------------------------------------------------
__global__ __launch_bounds__(256) void outp_mfma(
    const unsigned short* __restrict__ Ah, const unsigned short* __restrict__ Al,
    const unsigned short* __restrict__ W, const float* __restrict__ bias,
    float* __restrict__ out)
{
  __shared__ unsigned short Ahs[128 * 64];
  __shared__ unsigned short Als[128 * 64];
  __shared__ unsigned short Bs[128 * 64];

  const int tid = threadIdx.x;
  const int w = tid >> 6, l = tid & 63;
  const int l15 = l & 15, l4 = l >> 4;
  const int m0 = blockIdx.x << 7, n0 = blockIdx.y << 7;
  const int wr0 = (w >> 1) << 6, wc0 = (w & 1) << 6;

  f32x4 acc[4][4];
#pragma unroll
  for (int mt = 0; mt < 4; ++mt)
#pragma unroll
    for (int nt = 0; nt < 4; ++nt) acc[mt][nt] = (f32x4){0.f, 0.f, 0.f, 0.f};

  float bias4[4];
#pragma unroll
  for (int nt = 0; nt < 4; ++nt) bias4[nt] = bias[n0 + wc0 + (nt << 4) + l15];

  const int cbase = (w << 6) + l;

  for (int kt = 0; kt < 16; ++kt) {
    const int k0 = kt << 6;
    __syncthreads();
#pragma unroll
    for (int i = 0; i < 4; ++i) {
      const int c = cbase + (i << 8);
      const int r = c >> 3, kc = c & 7;
      char* ldsAh = (char*)Ahs + (((i << 2) + w) << 10);
      char* ldsAl = (char*)Als + (((i << 2) + w) << 10);
      char* ldsB  = (char*)Bs  + (((i << 2) + w) << 10);
      gload16(Ah + (size_t)(m0 + r) * E_DIM + k0 + (kc << 3), ldsAh);
      gload16(Al + (size_t)(m0 + r) * E_DIM + k0 + (kc << 3), ldsAl);
      gload16(W  + (size_t)(n0 + r) * E_DIM + k0 + (kc << 3), ldsB);
    }
    __syncthreads();
#pragma unroll
    for (int kh = 0; kh < 2; ++kh) {
      s16x8 ah[4], al[4], bfr[4];
      const int ko = (kh << 5) + (l4 << 3);
#pragma unroll
      for (int mt = 0; mt < 4; ++mt) {
        ah[mt] = *(const s16x8*)&Ahs[(wr0 + (mt << 4) + l15) * 64 + ko];
        al[mt] = *(const s16x8*)&Als[(wr0 + (mt << 4) + l15) * 64 + ko];
      }
#pragma unroll
      for (int nt = 0; nt < 4; ++nt)
        bfr[nt] = *(const s16x8*)&Bs[(wc0 + (nt << 4) + l15) * 64 + ko];
#pragma unroll
      for (int mt = 0; mt < 4; ++mt)
#pragma unroll
        for (int nt = 0; nt < 4; ++nt) {
          acc[mt][nt] = __builtin_amdgcn_mfma_f32_16x16x32_bf16(
              ah[mt], bfr[nt], acc[mt][nt], 0, 0, 0);
          acc[mt][nt] = __builtin_amdgcn_mfma_f32_16x16x32_bf16(
              al[mt], bfr[nt], acc[mt][nt], 0, 0, 0);
        }
    }
  }

#pragma unroll
  for (int mt = 0; mt < 4; ++mt)
#pragma unroll
    for (int nt = 0; nt < 4; ++nt) {
      const int n = n0 + wc0 + (nt << 4) + l15;
      const f32x4 c = acc[mt][nt];
#pragma unroll
      for (int r = 0; r < 4; ++r) {
        const int m = m0 + wr0 + (mt << 4) + (l4 << 2) + r;
        const int b = m >> 10, s = m & 1023;
        out[((size_t)s * B_SZ + b) * E_DIM + n] = c[r] + bias4[nt];
      }
    }
}

// ---------------------------------------------------------------------------
// bf16 MFMA flash attention, v2: T14 register-prefetch of all staging,
// incremental 128-col band ring (64 new cols / iter, wave-private rows),
// conflict-free Vt swizzle (chunk ^ (d&7) ^ ((d>>3)&7)).
// ---------------------------------------------------------------------------
__global__ __launch_bounds__(256) void attn_mfma(
    const unsigned short* __restrict__ Qb, const unsigned short* __restrict__ Kb,
    const unsigned short* __restrict__ Vb, const unsigned short* __restrict__ Rb,
    unsigned short* __restrict__ AOh, unsigned short* __restrict__ AOl)
{
  __shared__ unsigned short Ks[64 * 64];   // [j][d], slot = cb ^ (r&7)
  __shared__ unsigned short Rs[64 * 64];   // [r][d], slot = cb ^ (r&7)
  __shared__ unsigned short Vt[64 * 64];   // [d][j], slot = cb ^ (d&7) ^ ((d>>3)&7)
  __shared__ unsigned short Ps[64 * 64];   // [i][j], slot = cb ^ (i&7)
  __shared__ float band[64 * 132];         // ring: row i, slot 0..127

  const int tid = threadIdx.x;
  const int lane = tid & 63;
  const int w = tid >> 6;
  const int st = blockIdx.x & 15;
  const int bh = blockIdx.x >> 4;
  const int s0 = st << 6;
  const int bb = bh >> 4, hh = bh & 15;
  const size_t base = (size_t)bh * (S_LEN * HD);
  const int l15 = lane & 15, l4 = lane >> 4;
  const int rb_ = w << 4;                 // wave's q-row base

  // staging maps
  const int sr = tid >> 3, scb = tid & 7;          // K/R rows, chunk
  const int ksl = (scb ^ (sr & 7)) << 3;           // swizzled chunk slot
  const int jp = tid >> 3, vc = tid & 7;           // V: j-pair, d-chunk
  const int jc = jp >> 2, jlow = (jp & 3) << 1;

  const int rbase = 959 - s0;

  // Q fragments (A-operand: row=lane&15, k=(lane>>4)*8+e)
  s16x8 qf0, qf1;
  {
    const unsigned short* qp =
        Qb + base + (size_t)(s0 + rb_ + l15) * HD + (l4 << 3);
    qf0 = *(const s16x8*)(qp);
    qf1 = *(const s16x8*)(qp + 32);
  }

  f32x4 of[4];
  float mrow[4], lrow[4];
#pragma unroll
  for (int m = 0; m < 4; ++m) {
    of[m] = (f32x4){0.f, 0.f, 0.f, 0.f};
    mrow[m] = NEG_BIG; lrow[m] = 0.f;
  }

  // band MFMA + ring write for the block currently staged in Rs
#define BAND_MFMA(H0)                                                          \
  {                                                                            \
    f32x4 bq[4];                                                               \
    _Pragma("unroll") for (int rt = 0; rt < 4; ++rt)                           \
        bq[rt] = (f32x4){0.f, 0.f, 0.f, 0.f};                                  \
    _Pragma("unroll") for (int kk = 0; kk < 2; ++kk) {                         \
      const s16x8 qv = kk ? qf1 : qf0;                                         \
      const int cb = l4 + (kk << 2);                                           \
      _Pragma("unroll") for (int rt = 0; rt < 4; ++rt) {                       \
        const int r = (rt << 4) + l15;                                         \
        const s16x8 rf = *(const s16x8*)&Rs[(r << 6) + ((cb ^ (r & 7)) << 3)]; \
        bq[rt] = __builtin_amdgcn_mfma_f32_16x16x32_bf16(qv, rf, bq[rt], 0, 0, 0); \
      }                                                                        \
    }                                                                          \
    _Pragma("unroll") for (int rt = 0; rt < 4; ++rt)                           \
      _Pragma("unroll") for (int m = 0; m < 4; ++m)                            \
        band[(rb_ + (l4 << 2) + m) * 132 + (H0) + (rt << 4) + l15] = bq[rt][m];\
  }

  // ---- prologue: band blocks 0 and 1
  s16x8 Kr0, Kr1, Vr0, Vr1, Rr0, Rr1;
  {
    s16x8 tA0, tA1, tB0, tB1;
    tA0 = *(const s16x8*)(Rb + (size_t)clampg(rbase + sr) * HD + (scb << 3));
    tA1 = *(const s16x8*)(Rb + (size_t)clampg(rbase + 32 + sr) * HD + (scb << 3));
    tB0 = *(const s16x8*)(Rb + (size_t)clampg(rbase + 64 + sr) * HD + (scb << 3));
    tB1 = *(const s16x8*)(Rb + (size_t)clampg(rbase + 96 + sr) * HD + (scb << 3));
    *(s16x8*)&Rs[(sr << 6) + ksl] = tA0;
    *(s16x8*)&Rs[((sr + 32) << 6) + ksl] = tA1;
    __syncthreads();
    BAND_MFMA(0);
    // prefetch tile 0 K,V and R block 2
    Kr0 = *(const s16x8*)(Kb + base + (size_t)sr * HD + (scb << 3));
    Kr1 = *(const s16x8*)(Kb + base + (size_t)(32 + sr) * HD + (scb << 3));
    Vr0 = *(const s16x8*)(Vb + base + (size_t)(jp << 1) * HD + (vc << 3));
    Vr1 = *(const s16x8*)(Vb + base + (size_t)((jp << 1) + 1) * HD + (vc << 3));
    Rr0 = *(const s16x8*)(Rb + (size_t)clampg(rbase + 128 + sr) * HD + (scb << 3));
    Rr1 = *(const s16x8*)(Rb + (size_t)clampg(rbase + 160 + sr) * HD + (scb << 3));
    __syncthreads();               // all waves done reading Rs (block 0)
    *(s16x8*)&Rs[(sr << 6) + ksl] = tB0;
    *(s16x8*)&Rs[((sr + 32) << 6) + ksl] = tB1;
    __syncthreads();
    BAND_MFMA(64);
  }

  for (int tt = 0; tt < 16; ++tt) {
    const int t0 = tt << 6;
    __syncthreads();   // previous compute (and prologue BAND(64)) done with LDS

    // ---- stage prefetched regs -> LDS
    *(s16x8*)&Ks[(sr << 6) + ksl] = Kr0;
    *(s16x8*)&Ks[((sr + 32) << 6) + ksl] = Kr1;
    *(s16x8*)&Rs[(sr << 6) + ksl] = Rr0;
    *(s16x8*)&Rs[((sr + 32) << 6) + ksl] = Rr1;
#pragma unroll
    for (int e = 0; e < 8; ++e) {
      const int d = (vc << 3) + e;
      const int slot = jc ^ e ^ vc;
      const unsigned int pack = (unsigned int)(unsigned short)Vr0[e] |
                                ((unsigned int)(unsigned short)Vr1[e] << 16);
      *(unsigned int*)&Vt[(d << 6) + (slot << 3) + jlow] = pack;
    }
    __syncthreads();

    // ---- prefetch next tile (K,V) and R block tt+3
    if (tt < 15) {
      const int tn = t0 + 64;
      Kr0 = *(const s16x8*)(Kb + base + (size_t)(tn + sr) * HD + (scb << 3));
      Kr1 = *(const s16x8*)(Kb + base + (size_t)(tn + 32 + sr) * HD + (scb << 3));
      Vr0 = *(const s16x8*)(Vb + base + (size_t)(tn + (jp << 1)) * HD + (vc << 3));
      Vr1 = *(const s16x8*)(Vb + base + (size_t)(tn + (jp << 1) + 1) * HD + (vc << 3));
      const int gb = rbase + ((tt + 3) << 6) + sr;
      Rr0 = *(const s16x8*)(Rb + (size_t)clampg(gb) * HD + (scb << 3));
      Rr1 = *(const s16x8*)(Rb + (size_t)clampg(gb + 32) * HD + (scb << 3));
    }

    // ---- content MFMA
    f32x4 cf[4];
#pragma unroll
    for (int jt = 0; jt < 4; ++jt) cf[jt] = (f32x4){0.f, 0.f, 0.f, 0.f};
#pragma unroll
    for (int kk = 0; kk < 2; ++kk) {
      const s16x8 qv = kk ? qf1 : qf0;
      const int cb = l4 + (kk << 2);
#pragma unroll
      for (int jt = 0; jt < 4; ++jt) {
        const int r = (jt << 4) + l15;
        const s16x8 kf = *(const s16x8*)&Ks[(r << 6) + ((cb ^ (r & 7)) << 3)];
        cf[jt] = __builtin_amdgcn_mfma_f32_16x16x32_bf16(qv, kf, cf[jt], 0, 0, 0);
      }
    }

    // ---- online softmax with ring-band gather; P -> LDS (own rows)
#pragma unroll
    for (int m = 0; m < 4; ++m) {
      const int irow = rb_ + (l4 << 2) + m;
      const int bc = t0 + 63 - irow;
      const float* bp = &band[irow * 132];
      float sv[4];
#pragma unroll
      for (int jt = 0; jt < 4; ++jt)
        sv[jt] = cf[jt][m] + bp[(bc + (jt << 4) + l15) & 127];
      float mx = fmaxf(fmaxf(sv[0], sv[1]), fmaxf(sv[2], sv[3]));
      mx = fmaxf(mx, __shfl_xor(mx, 1));
      mx = fmaxf(mx, __shfl_xor(mx, 2));
      mx = fmaxf(mx, __shfl_xor(mx, 4));
      mx = fmaxf(mx, __shfl_xor(mx, 8));
      const float mnew = fmaxf(mrow[m], mx);
      const float alpha = __expf(mrow[m] - mnew);
      float p[4], ls = 0.f;
#pragma unroll
      for (int jt = 0; jt < 4; ++jt) { p[jt] = __expf(sv[jt] - mnew); ls += p[jt]; }
      ls += __shfl_xor(ls, 1); ls += __shfl_xor(ls, 2);
      ls += __shfl_xor(ls, 4); ls += __shfl_xor(ls, 8);
      lrow[m] = lrow[m] * alpha + ls;
      mrow[m] = mnew;
#pragma unroll
      for (int dt = 0; dt < 4; ++dt) of[dt][m] *= alpha;
#pragma unroll
      for (int jt = 0; jt < 4; ++jt) {
        const int col = (jt << 4) + l15;
        const int ch = col >> 3;
        Ps[(irow << 6) + ((ch ^ (irow & 7)) << 3) + (col & 7)] = f2bf(p[jt]);
      }
    }

    // ---- band MFMA for block tt+2 -> ring half (tt&1)  (wave-private rows)
    BAND_MFMA((tt & 1) << 6);

    // ---- PV: O += P @ V  (A = P own rows, B = Vt)
#pragma unroll
    for (int kk = 0; kk < 2; ++kk) {
      const int cb = l4 + (kk << 2);
      const int pr = rb_ + l15;
      const s16x8 pf = *(const s16x8*)&Ps[(pr << 6) + ((cb ^ (pr & 7)) << 3)];
#pragma unroll
      for (int dt = 0; dt < 4; ++dt) {
        const int dr = (dt << 4) + l15;
        const int slot = cb ^ (dr & 7) ^ ((dt << 1) + (l15 >> 3));
        const s16x8 vf = *(const s16x8*)&Vt[(dr << 6) + (slot << 3)];
        of[dt] = __builtin_amdgcn_mfma_f32_16x16x32_bf16(pf, vf, of[dt], 0, 0, 0);
      }
    }
  }

  // ---- epilogue: hi/lo bf16 split of normalized output, [B,S,E] e=h*64+d
#pragma unroll
  for (int m = 0; m < 4; ++m) {
    const float inv = 1.f / lrow[m];
    const int srow = s0 + rb_ + (l4 << 2) + m;
    const size_t off0 = ((size_t)bb * S_LEN + srow) * E_DIM + (hh << 6) + l15;
#pragma unroll
    for (int dt = 0; dt < 4; ++dt) {
      const float x = of[dt][m] * inv;
      const unsigned short hi = f2bf(x);
      AOh[off0 + (dt << 4)] = hi;
      AOl[off0 + (dt << 4)] = f2bf(x - bf2f(hi));
    }
  }
#undef BAND_MFMA
}

// ---------------------------------------------------------------------------
extern "C" void kernel_launch(void* const* d_in, const int* in_sizes, int n_in,
                              void* d_out, int out_size, void* d_ws, size_t ws_size,
                              hipStream_t stream) {
  (void)in_sizes; (void)n_in; (void)out_size; (void)ws_size;
  const float* query = (const float*)d_in[0];
  const float* key   = (const float*)d_in[1];
  const float* value = (const float*)d_in[2];
  const float* Wq = (const float*)d_in[3];
  const float* bq = (const float*)d_in[4];
  const float* Wk = (const float*)d_in[5];
  const float* bk = (const float*)d_in[6];
  const float* Wv = (const float*)d_in[7];
  const float* bv = (const float*)d_in[8];
  const float* Wo = (const float*)d_in[9];
  const float* bo = (const float*)d_in[10];
  const float* tbl = (const float*)d_in[11];

  const size_t per = (size_t)B_SZ * H_NUM * S_LEN * HD;   // 4,194,304 elems
  const size_t wsz = (size_t)E_DIM * E_DIM;               // 1,048,576 elems
  unsigned short* p = (unsigned short*)d_ws;
  unsigned short* wsQb = p; p += per;
  unsigned short* wsKb = p; p += per;
  unsigned short* wsVb = p; p += per;
  unsigned short* wsRb = p; p += 131072;
  unsigned short* wsXq = p; p += per;
  unsigned short* wsXk = p; p += per;
  unsigned short* wsXv = p; p += per;
  unsigned short* wsWq = p; p += wsz;
  unsigned short* wsWk = p; p += wsz;
  unsigned short* wsWv = p; p += wsz;
  unsigned short* wsWo = p; p += wsz;
  unsigned short* wsAh = p; p += per;
  unsigned short* wsAl = p; p += per;
  float* out = (float*)d_out;

  dim3 blk(256);
  hipLaunchKernelGGL(conv_all, dim3(8256), blk, 0, stream,
                     query, key, value, Wq, Wk, Wv, Wo, tbl,
                     wsXq, wsXk, wsXv, wsWq, wsWk, wsWv, wsWo, wsRb);
  hipLaunchKernelGGL(qkv_mfma, dim3(32, 8, 3), blk, 0, stream,
                     wsXq, wsXk, wsXv, wsWq, wsWk, wsWv, bq, bk, bv,
                     wsQb, wsKb, wsVb);
  hipLaunchKernelGGL(attn_mfma, dim3(1024), blk, 0, stream,
                     wsQb, wsKb, wsVb, wsRb, wsAh, wsAl);
  hipLaunchKernelGGL(outp_mfma, dim3(32, 8), blk, 0, stream,
                     wsAh, wsAl, wsWo, bo, out);
}

// Round 7
// 175.743 us; speedup vs baseline: 6.5010x; 1.0285x over previous
//
#include <hip/hip_runtime.h>
#include <math.h>

#define S_LEN 1024
#define B_SZ 4
#define E_DIM 1024
#define H_NUM 16
#define HD 64
#define IDX_MAX 2044   // clip(dist,-1022,1022)+1022 in [0,2044]
#define NEG_BIG (-3.0e38f)

typedef __attribute__((ext_vector_type(8))) short s16x8;   // 8 bf16 (4 VGPRs)
typedef __attribute__((ext_vector_type(4))) float f32x4;

__device__ __forceinline__ unsigned short f2bf(float f) {
  union { float f; unsigned int u; } v; v.f = f;
  return (unsigned short)((v.u + 0x7FFFu + ((v.u >> 16) & 1u)) >> 16);  // RNE
}
__device__ __forceinline__ float bf2f(unsigned short h) {
  union { unsigned int u; float f; } v; v.u = ((unsigned int)h) << 16;
  return v.f;
}
__device__ __forceinline__ void gload16(const void* g, void* l) {
  __builtin_amdgcn_global_load_lds(
      (const __attribute__((address_space(1))) void*)g,
      (__attribute__((address_space(3))) void*)l, 16, 0, 0);
}
__device__ __forceinline__ int clampg(int g) {
  return g < 0 ? 0 : (g > IDX_MAX ? IDX_MAX : g);
}

// ---------------------------------------------------------------------------
// All fp32->bf16 conversions in one launch (8 segments).
// ---------------------------------------------------------------------------
__global__ __launch_bounds__(256) void conv_all(
    const float* __restrict__ q, const float* __restrict__ k,
    const float* __restrict__ v, const float* __restrict__ wq,
    const float* __restrict__ wk, const float* __restrict__ wv,
    const float* __restrict__ wo, const float* __restrict__ tb,
    unsigned short* __restrict__ oq, unsigned short* __restrict__ ok,
    unsigned short* __restrict__ ov, unsigned short* __restrict__ owq,
    unsigned short* __restrict__ owk, unsigned short* __restrict__ owv,
    unsigned short* __restrict__ owo, unsigned short* __restrict__ otb)
{
  const int b = blockIdx.x;
  const float* src; unsigned short* dst; int n, lb;
  if (b < 2048)      { src = q;  dst = oq;  n = 4194304; lb = b; }
  else if (b < 4096) { src = k;  dst = ok;  n = 4194304; lb = b - 2048; }
  else if (b < 6144) { src = v;  dst = ov;  n = 4194304; lb = b - 4096; }
  else if (b < 6656) { src = wq; dst = owq; n = 1048576; lb = b - 6144; }
  else if (b < 7168) { src = wk; dst = owk; n = 1048576; lb = b - 6656; }
  else if (b < 7680) { src = wv; dst = owv; n = 1048576; lb = b - 7168; }
  else if (b < 8192) { src = wo; dst = owo; n = 1048576; lb = b - 7680; }
  else               { src = tb; dst = otb; n = 131008;  lb = b - 8192; }
  const int i = (lb * 256 + threadIdx.x) << 3;
  if (i >= n) return;
  const float4 a = *(const float4*)(src + i);
  const float4 c = *(const float4*)(src + i + 4);
  union { unsigned short us[8]; uint4 v4; } u;
  u.us[0] = f2bf(a.x); u.us[1] = f2bf(a.y); u.us[2] = f2bf(a.z); u.us[3] = f2bf(a.w);
  u.us[4] = f2bf(c.x); u.us[5] = f2bf(c.y); u.us[6] = f2bf(c.z); u.us[7] = f2bf(c.w);
  *(uint4*)(dst + i) = u.v4;
}

// ---------------------------------------------------------------------------
// Fused QKV projection (validated R3/R4): bf16 MFMA, 128x128 tile, BK=64.
// ---------------------------------------------------------------------------
__global__ __launch_bounds__(256, 3) void qkv_mfma(
    const unsigned short* __restrict__ X0, const unsigned short* __restrict__ X1,
    const unsigned short* __restrict__ X2,
    const unsigned short* __restrict__ W0, const unsigned short* __restrict__ W1,
    const unsigned short* __restrict__ W2,
    const float* __restrict__ bp0, const float* __restrict__ bp1,
    const float* __restrict__ bp2,
    unsigned short* __restrict__ O0, unsigned short* __restrict__ O1,
    unsigned short* __restrict__ O2)
{
  __shared__ unsigned short As[128 * 64];
  __shared__ unsigned short Bs[128 * 64];

  const int z = blockIdx.z;
  const unsigned short* X = z == 0 ? X0 : (z == 1 ? X1 : X2);
  const unsigned short* W = z == 0 ? W0 : (z == 1 ? W1 : W2);
  const float* bias = z == 0 ? bp0 : (z == 1 ? bp1 : bp2);
  unsigned short* O = z == 0 ? O0 : (z == 1 ? O1 : O2);
  const float scale = z == 0 ? 0.125f : 1.0f;

  const int tid = threadIdx.x;
  const int w = tid >> 6, l = tid & 63;
  const int l15 = l & 15, l4 = l >> 4;
  const int m0 = blockIdx.x << 7, n0 = blockIdx.y << 7;
  const int wr0 = (w >> 1) << 6, wc0 = (w & 1) << 6;

  f32x4 acc[4][4];
#pragma unroll
  for (int mt = 0; mt < 4; ++mt)
#pragma unroll
    for (int nt = 0; nt < 4; ++nt) acc[mt][nt] = (f32x4){0.f, 0.f, 0.f, 0.f};

  float bias4[4];
#pragma unroll
  for (int nt = 0; nt < 4; ++nt) bias4[nt] = bias[n0 + wc0 + (nt << 4) + l15];

  const int cbase = (w << 6) + l;

  for (int kt = 0; kt < 16; ++kt) {
    const int k0 = kt << 6;
    __syncthreads();
#pragma unroll
    for (int i = 0; i < 4; ++i) {
      const int c = cbase + (i << 8);
      const int r = c >> 3, kc = c & 7;
      char* ldsA = (char*)As + (((i << 2) + w) << 10);
      char* ldsB = (char*)Bs + (((i << 2) + w) << 10);
      gload16(X + (size_t)(m0 + r) * E_DIM + k0 + (kc << 3), ldsA);
      gload16(W + (size_t)(n0 + r) * E_DIM + k0 + (kc << 3), ldsB);
    }
    __syncthreads();
#pragma unroll
    for (int kh = 0; kh < 2; ++kh) {
      s16x8 af[4], bfr[4];
#pragma unroll
      for (int mt = 0; mt < 4; ++mt)
        af[mt] = *(const s16x8*)&As[(wr0 + (mt << 4) + l15) * 64 + (kh << 5) + (l4 << 3)];
#pragma unroll
      for (int nt = 0; nt < 4; ++nt)
        bfr[nt] = *(const s16x8*)&Bs[(wc0 + (nt << 4) + l15) * 64 + (kh << 5) + (l4 << 3)];
#pragma unroll
      for (int mt = 0; mt < 4; ++mt)
#pragma unroll
        for (int nt = 0; nt < 4; ++nt)
          acc[mt][nt] = __builtin_amdgcn_mfma_f32_16x16x32_bf16(
              af[mt], bfr[nt], acc[mt][nt], 0, 0, 0);
    }
  }

#pragma unroll
  for (int mt = 0; mt < 4; ++mt)
#pragma unroll
    for (int nt = 0; nt < 4; ++nt) {
      const int n = n0 + wc0 + (nt << 4) + l15;
      const int h = n >> 6, d = n & 63;
      const f32x4 c = acc[mt][nt];
#pragma unroll
      for (int r = 0; r < 4; ++r) {
        const int m = m0 + wr0 + (mt << 4) + (l4 << 2) + r;
        const int s = m >> 2, b = m & 3;
        O[((((size_t)b * H_NUM + h) * S_LEN) + s) * HD + d] =
            f2bf((c[r] + bias4[nt]) * scale);
      }
    }
}

// ---------------------------------------------------------------------------
// Output projection with hi/lo split A (validated R3/R4).
// ---------------------------------------------------------------------------
__global__ __launch_bounds__(256) void outp_mfma(
    const unsigned short* __restrict__ Ah, const unsigned short* __restrict__ Al,
    const unsigned short* __restrict__ W, const float* __restrict__ bias,
    float* __restrict__ out)
{
  __shared__ unsigned short Ahs[128 * 64];
  __shared__ unsigned short Als[128 * 64];
  __shared__ unsigned short Bs[128 * 64];

  const int tid = threadIdx.x;
  const int w = tid >> 6, l = tid & 63;
  const int l15 = l & 15, l4 = l >> 4;
  const int m0 = blockIdx.x << 7, n0 = blockIdx.y << 7;
  const int wr0 = (w >> 1) << 6, wc0 = (w & 1) << 6;

  f32x4 acc[4][4];
#pragma unroll
  for (int mt = 0; mt < 4; ++mt)
#pragma unroll
    for (int nt = 0; nt < 4; ++nt) acc[mt][nt] = (f32x4){0.f, 0.f, 0.f, 0.f};

  float bias4[4];
#pragma unroll
  for (int nt = 0; nt < 4; ++nt) bias4[nt] = bias[n0 + wc0 + (nt << 4) + l15];

  const int cbase = (w << 6) + l;

  for (int kt = 0; kt < 16; ++kt) {
    const int k0 = kt << 6;
    __syncthreads();
#pragma unroll
    for (int i = 0; i < 4; ++i) {
      const int c = cbase + (i << 8);
      const int r = c >> 3, kc = c & 7;
      char* ldsAh = (char*)Ahs + (((i << 2) + w) << 10);
      char* ldsAl = (char*)Als + (((i << 2) + w) << 10);
      char* ldsB  = (char*)Bs  + (((i << 2) + w) << 10);
      gload16(Ah + (size_t)(m0 + r) * E_DIM + k0 + (kc << 3), ldsAh);
      gload16(Al + (size_t)(m0 + r) * E_DIM + k0 + (kc << 3), ldsAl);
      gload16(W  + (size_t)(n0 + r) * E_DIM + k0 + (kc << 3), ldsB);
    }
    __syncthreads();
#pragma unroll
    for (int kh = 0; kh < 2; ++kh) {
      s16x8 ah[4], al[4], bfr[4];
      const int ko = (kh << 5) + (l4 << 3);
#pragma unroll
      for (int mt = 0; mt < 4; ++mt) {
        ah[mt] = *(const s16x8*)&Ahs[(wr0 + (mt << 4) + l15) * 64 + ko];
        al[mt] = *(const s16x8*)&Als[(wr0 + (mt << 4) + l15) * 64 + ko];
      }
#pragma unroll
      for (int nt = 0; nt < 4; ++nt)
        bfr[nt] = *(const s16x8*)&Bs[(wc0 + (nt << 4) + l15) * 64 + ko];
#pragma unroll
      for (int mt = 0; mt < 4; ++mt)
#pragma unroll
        for (int nt = 0; nt < 4; ++nt) {
          acc[mt][nt] = __builtin_amdgcn_mfma_f32_16x16x32_bf16(
              ah[mt], bfr[nt], acc[mt][nt], 0, 0, 0);
          acc[mt][nt] = __builtin_amdgcn_mfma_f32_16x16x32_bf16(
              al[mt], bfr[nt], acc[mt][nt], 0, 0, 0);
        }
    }
  }

#pragma unroll
  for (int mt = 0; mt < 4; ++mt)
#pragma unroll
    for (int nt = 0; nt < 4; ++nt) {
      const int n = n0 + wc0 + (nt << 4) + l15;
      const f32x4 c = acc[mt][nt];
#pragma unroll
      for (int r = 0; r < 4; ++r) {
        const int m = m0 + wr0 + (mt << 4) + (l4 << 2) + r;
        const int b = m >> 10, s = m & 1023;
        out[((size_t)s * B_SZ + b) * E_DIM + n] = c[r] + bias4[nt];
      }
    }
}

// ---------------------------------------------------------------------------
// bf16 MFMA flash attention (validated R4 structure): T14 register-prefetch,
// incremental 128-col fp32 band ring, conflict-free Vt swizzle.
// R6 delta vs R4: T5 s_setprio(1) around the three MFMA clusters only.
// ---------------------------------------------------------------------------
__global__ __launch_bounds__(256) void attn_mfma(
    const unsigned short* __restrict__ Qb, const unsigned short* __restrict__ Kb,
    const unsigned short* __restrict__ Vb, const unsigned short* __restrict__ Rb,
    unsigned short* __restrict__ AOh, unsigned short* __restrict__ AOl)
{
  __shared__ unsigned short Ks[64 * 64];   // [j][d], slot = cb ^ (r&7)
  __shared__ unsigned short Rs[64 * 64];   // [r][d], slot = cb ^ (r&7)
  __shared__ unsigned short Vt[64 * 64];   // [d][j], slot = cb ^ (d&7) ^ ((d>>3)&7)
  __shared__ unsigned short Ps[64 * 64];   // [i][j], slot = cb ^ (i&7)
  __shared__ float band[64 * 132];         // ring: row i, slot 0..127

  const int tid = threadIdx.x;
  const int lane = tid & 63;
  const int w = tid >> 6;
  const int st = blockIdx.x & 15;
  const int bh = blockIdx.x >> 4;
  const int s0 = st << 6;
  const int bb = bh >> 4, hh = bh & 15;
  const size_t base = (size_t)bh * (S_LEN * HD);
  const int l15 = lane & 15, l4 = lane >> 4;
  const int rb_ = w << 4;                 // wave's q-row base

  // staging maps
  const int sr = tid >> 3, scb = tid & 7;          // K/R rows, chunk
  const int ksl = (scb ^ (sr & 7)) << 3;           // swizzled chunk slot
  const int jp = tid >> 3, vc = tid & 7;           // V: j-pair, d-chunk
  const int jc = jp >> 2, jlow = (jp & 3) << 1;

  const int rbase = 959 - s0;

  // Q fragments (A-operand: row=lane&15, k=(lane>>4)*8+e)
  s16x8 qf0, qf1;
  {
    const unsigned short* qp =
        Qb + base + (size_t)(s0 + rb_ + l15) * HD + (l4 << 3);
    qf0 = *(const s16x8*)(qp);
    qf1 = *(const s16x8*)(qp + 32);
  }

  f32x4 of[4];
  float mrow[4], lrow[4];
#pragma unroll
  for (int m = 0; m < 4; ++m) {
    of[m] = (f32x4){0.f, 0.f, 0.f, 0.f};
    mrow[m] = NEG_BIG; lrow[m] = 0.f;
  }

  // band MFMA + ring write for the block currently staged in Rs
#define BAND_MFMA(H0)                                                          \
  {                                                                            \
    f32x4 bq[4];                                                               \
    _Pragma("unroll") for (int rt = 0; rt < 4; ++rt)                           \
        bq[rt] = (f32x4){0.f, 0.f, 0.f, 0.f};                                  \
    __builtin_amdgcn_s_setprio(1);                                             \
    _Pragma("unroll") for (int kk = 0; kk < 2; ++kk) {                         \
      const s16x8 qv = kk ? qf1 : qf0;                                         \
      const int cb = l4 + (kk << 2);                                           \
      _Pragma("unroll") for (int rt = 0; rt < 4; ++rt) {                       \
        const int r = (rt << 4) + l15;                                         \
        const s16x8 rf = *(const s16x8*)&Rs[(r << 6) + ((cb ^ (r & 7)) << 3)]; \
        bq[rt] = __builtin_amdgcn_mfma_f32_16x16x32_bf16(qv, rf, bq[rt], 0, 0, 0); \
      }                                                                        \
    }                                                                          \
    __builtin_amdgcn_s_setprio(0);                                             \
    _Pragma("unroll") for (int rt = 0; rt < 4; ++rt)                           \
      _Pragma("unroll") for (int m = 0; m < 4; ++m)                            \
        band[(rb_ + (l4 << 2) + m) * 132 + (H0) + (rt << 4) + l15] = bq[rt][m];\
  }

  // ---- prologue: band blocks 0 and 1
  s16x8 Kr0, Kr1, Vr0, Vr1, Rr0, Rr1;
  {
    s16x8 tA0, tA1, tB0, tB1;
    tA0 = *(const s16x8*)(Rb + (size_t)clampg(rbase + sr) * HD + (scb << 3));
    tA1 = *(const s16x8*)(Rb + (size_t)clampg(rbase + 32 + sr) * HD + (scb << 3));
    tB0 = *(const s16x8*)(Rb + (size_t)clampg(rbase + 64 + sr) * HD + (scb << 3));
    tB1 = *(const s16x8*)(Rb + (size_t)clampg(rbase + 96 + sr) * HD + (scb << 3));
    *(s16x8*)&Rs[(sr << 6) + ksl] = tA0;
    *(s16x8*)&Rs[((sr + 32) << 6) + ksl] = tA1;
    __syncthreads();
    BAND_MFMA(0);
    // prefetch tile 0 K,V and R block 2
    Kr0 = *(const s16x8*)(Kb + base + (size_t)sr * HD + (scb << 3));
    Kr1 = *(const s16x8*)(Kb + base + (size_t)(32 + sr) * HD + (scb << 3));
    Vr0 = *(const s16x8*)(Vb + base + (size_t)(jp << 1) * HD + (vc << 3));
    Vr1 = *(const s16x8*)(Vb + base + (size_t)((jp << 1) + 1) * HD + (vc << 3));
    Rr0 = *(const s16x8*)(Rb + (size_t)clampg(rbase + 128 + sr) * HD + (scb << 3));
    Rr1 = *(const s16x8*)(Rb + (size_t)clampg(rbase + 160 + sr) * HD + (scb << 3));
    __syncthreads();               // all waves done reading Rs (block 0)
    *(s16x8*)&Rs[(sr << 6) + ksl] = tB0;
    *(s16x8*)&Rs[((sr + 32) << 6) + ksl] = tB1;
    __syncthreads();
    BAND_MFMA(64);
  }

  for (int tt = 0; tt < 16; ++tt) {
    const int t0 = tt << 6;
    __syncthreads();   // previous compute (and prologue BAND(64)) done with LDS

    // ---- stage prefetched regs -> LDS
    *(s16x8*)&Ks[(sr << 6) + ksl] = Kr0;
    *(s16x8*)&Ks[((sr + 32) << 6) + ksl] = Kr1;
    *(s16x8*)&Rs[(sr << 6) + ksl] = Rr0;
    *(s16x8*)&Rs[((sr + 32) << 6) + ksl] = Rr1;
#pragma unroll
    for (int e = 0; e < 8; ++e) {
      const int d = (vc << 3) + e;
      const int slot = jc ^ e ^ vc;
      const unsigned int pack = (unsigned int)(unsigned short)Vr0[e] |
                                ((unsigned int)(unsigned short)Vr1[e] << 16);
      *(unsigned int*)&Vt[(d << 6) + (slot << 3) + jlow] = pack;
    }
    __syncthreads();

    // ---- prefetch next tile (K,V) and R block tt+3
    if (tt < 15) {
      const int tn = t0 + 64;
      Kr0 = *(const s16x8*)(Kb + base + (size_t)(tn + sr) * HD + (scb << 3));
      Kr1 = *(const s16x8*)(Kb + base + (size_t)(tn + 32 + sr) * HD + (scb << 3));
      Vr0 = *(const s16x8*)(Vb + base + (size_t)(tn + (jp << 1)) * HD + (vc << 3));
      Vr1 = *(const s16x8*)(Vb + base + (size_t)(tn + (jp << 1) + 1) * HD + (vc << 3));
      const int gb = rbase + ((tt + 3) << 6) + sr;
      Rr0 = *(const s16x8*)(Rb + (size_t)clampg(gb) * HD + (scb << 3));
      Rr1 = *(const s16x8*)(Rb + (size_t)clampg(gb + 32) * HD + (scb << 3));
    }

    // ---- content MFMA
    f32x4 cf[4];
#pragma unroll
    for (int jt = 0; jt < 4; ++jt) cf[jt] = (f32x4){0.f, 0.f, 0.f, 0.f};
    __builtin_amdgcn_s_setprio(1);
#pragma unroll
    for (int kk = 0; kk < 2; ++kk) {
      const s16x8 qv = kk ? qf1 : qf0;
      const int cb = l4 + (kk << 2);
#pragma unroll
      for (int jt = 0; jt < 4; ++jt) {
        const int r = (jt << 4) + l15;
        const s16x8 kf = *(const s16x8*)&Ks[(r << 6) + ((cb ^ (r & 7)) << 3)];
        cf[jt] = __builtin_amdgcn_mfma_f32_16x16x32_bf16(qv, kf, cf[jt], 0, 0, 0);
      }
    }
    __builtin_amdgcn_s_setprio(0);

    // ---- online softmax with ring-band gather; P -> LDS (own rows)
#pragma unroll
    for (int m = 0; m < 4; ++m) {
      const int irow = rb_ + (l4 << 2) + m;
      const int bc = t0 + 63 - irow;
      const float* bp = &band[irow * 132];
      float sv[4];
#pragma unroll
      for (int jt = 0; jt < 4; ++jt)
        sv[jt] = cf[jt][m] + bp[(bc + (jt << 4) + l15) & 127];
      float mx = fmaxf(fmaxf(sv[0], sv[1]), fmaxf(sv[2], sv[3]));
      mx = fmaxf(mx, __shfl_xor(mx, 1));
      mx = fmaxf(mx, __shfl_xor(mx, 2));
      mx = fmaxf(mx, __shfl_xor(mx, 4));
      mx = fmaxf(mx, __shfl_xor(mx, 8));
      const float mnew = fmaxf(mrow[m], mx);
      const float alpha = __expf(mrow[m] - mnew);
      float p[4], ls = 0.f;
#pragma unroll
      for (int jt = 0; jt < 4; ++jt) { p[jt] = __expf(sv[jt] - mnew); ls += p[jt]; }
      ls += __shfl_xor(ls, 1); ls += __shfl_xor(ls, 2);
      ls += __shfl_xor(ls, 4); ls += __shfl_xor(ls, 8);
      lrow[m] = lrow[m] * alpha + ls;
      mrow[m] = mnew;
#pragma unroll
      for (int dt = 0; dt < 4; ++dt) of[dt][m] *= alpha;
#pragma unroll
      for (int jt = 0; jt < 4; ++jt) {
        const int col = (jt << 4) + l15;
        const int ch = col >> 3;
        Ps[(irow << 6) + ((ch ^ (irow & 7)) << 3) + (col & 7)] = f2bf(p[jt]);
      }
    }

    // ---- band MFMA for block tt+2 -> ring half (tt&1)  (wave-private rows)
    BAND_MFMA((tt & 1) << 6);

    // ---- PV: O += P @ V  (A = P own rows, B = Vt)
    __builtin_amdgcn_s_setprio(1);
#pragma unroll
    for (int kk = 0; kk < 2; ++kk) {
      const int cb = l4 + (kk << 2);
      const int pr = rb_ + l15;
      const s16x8 pf = *(const s16x8*)&Ps[(pr << 6) + ((cb ^ (pr & 7)) << 3)];
#pragma unroll
      for (int dt = 0; dt < 4; ++dt) {
        const int dr = (dt << 4) + l15;
        const int slot = cb ^ (dr & 7) ^ ((dt << 1) + (l15 >> 3));
        const s16x8 vf = *(const s16x8*)&Vt[(dr << 6) + (slot << 3)];
        of[dt] = __builtin_amdgcn_mfma_f32_16x16x32_bf16(pf, vf, of[dt], 0, 0, 0);
      }
    }
    __builtin_amdgcn_s_setprio(0);
  }

  // ---- epilogue: hi/lo bf16 split of normalized output, [B,S,E] e=h*64+d
#pragma unroll
  for (int m = 0; m < 4; ++m) {
    const float inv = 1.f / lrow[m];
    const int srow = s0 + rb_ + (l4 << 2) + m;
    const size_t off0 = ((size_t)bb * S_LEN + srow) * E_DIM + (hh << 6) + l15;
#pragma unroll
    for (int dt = 0; dt < 4; ++dt) {
      const float x = of[dt][m] * inv;
      const unsigned short hi = f2bf(x);
      AOh[off0 + (dt << 4)] = hi;
      AOl[off0 + (dt << 4)] = f2bf(x - bf2f(hi));
    }
  }
#undef BAND_MFMA
}

// ---------------------------------------------------------------------------
extern "C" void kernel_launch(void* const* d_in, const int* in_sizes, int n_in,
                              void* d_out, int out_size, void* d_ws, size_t ws_size,
                              hipStream_t stream) {
  (void)in_sizes; (void)n_in; (void)out_size; (void)ws_size;
  const float* query = (const float*)d_in[0];
  const float* key   = (const float*)d_in[1];
  const float* value = (const float*)d_in[2];
  const float* Wq = (const float*)d_in[3];
  const float* bq = (const float*)d_in[4];
  const float* Wk = (const float*)d_in[5];
  const float* bk = (const float*)d_in[6];
  const float* Wv = (const float*)d_in[7];
  const float* bv = (const float*)d_in[8];
  const float* Wo = (const float*)d_in[9];
  const float* bo = (const float*)d_in[10];
  const float* tbl = (const float*)d_in[11];

  const size_t per = (size_t)B_SZ * H_NUM * S_LEN * HD;   // 4,194,304 elems
  const size_t wsz = (size_t)E_DIM * E_DIM;               // 1,048,576 elems
  unsigned short* p = (unsigned short*)d_ws;
  unsigned short* wsQb = p; p += per;
  unsigned short* wsKb = p; p += per;
  unsigned short* wsVb = p; p += per;
  unsigned short* wsRb = p; p += 131072;
  unsigned short* wsXq = p; p += per;
  unsigned short* wsXk = p; p += per;
  unsigned short* wsXv = p; p += per;
  unsigned short* wsWq = p; p += wsz;
  unsigned short* wsWk = p; p += wsz;
  unsigned short* wsWv = p; p += wsz;
  unsigned short* wsWo = p; p += wsz;
  unsigned short* wsAh = p; p += per;
  unsigned short* wsAl = p; p += per;
  float* out = (float*)d_out;

  dim3 blk(256);
  hipLaunchKernelGGL(conv_all, dim3(8256), blk, 0, stream,
                     query, key, value, Wq, Wk, Wv, Wo, tbl,
                     wsXq, wsXk, wsXv, wsWq, wsWk, wsWv, wsWo, wsRb);
  hipLaunchKernelGGL(qkv_mfma, dim3(32, 8, 3), blk, 0, stream,
                     wsXq, wsXk, wsXv, wsWq, wsWk, wsWv, bq, bk, bv,
                     wsQb, wsKb, wsVb);
  hipLaunchKernelGGL(attn_mfma, dim3(1024), blk, 0, stream,
                     wsQb, wsKb, wsVb, wsRb, wsAh, wsAl);
  hipLaunchKernelGGL(outp_mfma, dim3(32, 8), blk, 0, stream,
                     wsAh, wsAl, wsWo, bo, out);
}

// Round 8
// 163.233 us; speedup vs baseline: 6.9992x; 1.0766x over previous
//
#include <hip/hip_runtime.h>
#include <math.h>

#define S_LEN 1024
#define B_SZ 4
#define E_DIM 1024
#define H_NUM 16
#define HD 64
#define IDX_MAX 2044   // clip(dist,-1022,1022)+1022 in [0,2044]
#define NEG_BIG (-3.0e38f)

typedef __attribute__((ext_vector_type(8))) short s16x8;   // 8 bf16 (4 VGPRs)
typedef __attribute__((ext_vector_type(4))) float f32x4;

__device__ __forceinline__ unsigned short f2bf(float f) {
  union { float f; unsigned int u; } v; v.f = f;
  return (unsigned short)((v.u + 0x7FFFu + ((v.u >> 16) & 1u)) >> 16);  // RNE
}
__device__ __forceinline__ float bf2f(unsigned short h) {
  union { unsigned int u; float f; } v; v.u = ((unsigned int)h) << 16;
  return v.f;
}
__device__ __forceinline__ void gload16(const void* g, void* l) {
  __builtin_amdgcn_global_load_lds(
      (const __attribute__((address_space(1))) void*)g,
      (__attribute__((address_space(3))) void*)l, 16, 0, 0);
}
__device__ __forceinline__ int clampg(int g) {
  return g < 0 ? 0 : (g > IDX_MAX ? IDX_MAX : g);
}

// ---- DPP 16-lane rotation butterfly reduces (VALU pipe, not LDS) ----------
// row_ror:N = dpp_ctrl 0x120+N; our reduce groups (fixed lane>>4) are exactly
// DPP rows, and ror{8,4,2,1} generates the full 16-group.
template <int CTRL>
__device__ __forceinline__ float dppror(float x) {
  union { float f; int i; } a, b;
  a.f = x;
  b.i = __builtin_amdgcn_update_dpp(a.i, a.i, CTRL, 0xF, 0xF, false);
  return b.f;
}
__device__ __forceinline__ float rmax16(float x) {
  x = fmaxf(x, dppror<0x128>(x));
  x = fmaxf(x, dppror<0x124>(x));
  x = fmaxf(x, dppror<0x122>(x));
  x = fmaxf(x, dppror<0x121>(x));
  return x;
}
__device__ __forceinline__ float rsum16(float x) {
  x += dppror<0x128>(x);
  x += dppror<0x124>(x);
  x += dppror<0x122>(x);
  x += dppror<0x121>(x);
  return x;
}

// ---------------------------------------------------------------------------
// All fp32->bf16 conversions in one launch (8 segments).
// ---------------------------------------------------------------------------
__global__ __launch_bounds__(256) void conv_all(
    const float* __restrict__ q, const float* __restrict__ k,
    const float* __restrict__ v, const float* __restrict__ wq,
    const float* __restrict__ wk, const float* __restrict__ wv,
    const float* __restrict__ wo, const float* __restrict__ tb,
    unsigned short* __restrict__ oq, unsigned short* __restrict__ ok,
    unsigned short* __restrict__ ov, unsigned short* __restrict__ owq,
    unsigned short* __restrict__ owk, unsigned short* __restrict__ owv,
    unsigned short* __restrict__ owo, unsigned short* __restrict__ otb)
{
  const int b = blockIdx.x;
  const float* src; unsigned short* dst; int n, lb;
  if (b < 2048)      { src = q;  dst = oq;  n = 4194304; lb = b; }
  else if (b < 4096) { src = k;  dst = ok;  n = 4194304; lb = b - 2048; }
  else if (b < 6144) { src = v;  dst = ov;  n = 4194304; lb = b - 4096; }
  else if (b < 6656) { src = wq; dst = owq; n = 1048576; lb = b - 6144; }
  else if (b < 7168) { src = wk; dst = owk; n = 1048576; lb = b - 6656; }
  else if (b < 7680) { src = wv; dst = owv; n = 1048576; lb = b - 7168; }
  else if (b < 8192) { src = wo; dst = owo; n = 1048576; lb = b - 7680; }
  else               { src = tb; dst = otb; n = 131008;  lb = b - 8192; }
  const int i = (lb * 256 + threadIdx.x) << 3;
  if (i >= n) return;
  const float4 a = *(const float4*)(src + i);
  const float4 c = *(const float4*)(src + i + 4);
  union { unsigned short us[8]; uint4 v4; } u;
  u.us[0] = f2bf(a.x); u.us[1] = f2bf(a.y); u.us[2] = f2bf(a.z); u.us[3] = f2bf(a.w);
  u.us[4] = f2bf(c.x); u.us[5] = f2bf(c.y); u.us[6] = f2bf(c.z); u.us[7] = f2bf(c.w);
  *(uint4*)(dst + i) = u.v4;
}

// ---------------------------------------------------------------------------
// Fused QKV projection (validated R3/R4): bf16 MFMA, 128x128 tile, BK=64.
// ---------------------------------------------------------------------------
__global__ __launch_bounds__(256, 3) void qkv_mfma(
    const unsigned short* __restrict__ X0, const unsigned short* __restrict__ X1,
    const unsigned short* __restrict__ X2,
    const unsigned short* __restrict__ W0, const unsigned short* __restrict__ W1,
    const unsigned short* __restrict__ W2,
    const float* __restrict__ bp0, const float* __restrict__ bp1,
    const float* __restrict__ bp2,
    unsigned short* __restrict__ O0, unsigned short* __restrict__ O1,
    unsigned short* __restrict__ O2)
{
  __shared__ unsigned short As[128 * 64];
  __shared__ unsigned short Bs[128 * 64];

  const int z = blockIdx.z;
  const unsigned short* X = z == 0 ? X0 : (z == 1 ? X1 : X2);
  const unsigned short* W = z == 0 ? W0 : (z == 1 ? W1 : W2);
  const float* bias = z == 0 ? bp0 : (z == 1 ? bp1 : bp2);
  unsigned short* O = z == 0 ? O0 : (z == 1 ? O1 : O2);
  const float scale = z == 0 ? 0.125f : 1.0f;

  const int tid = threadIdx.x;
  const int w = tid >> 6, l = tid & 63;
  const int l15 = l & 15, l4 = l >> 4;
  const int m0 = blockIdx.x << 7, n0 = blockIdx.y << 7;
  const int wr0 = (w >> 1) << 6, wc0 = (w & 1) << 6;

  f32x4 acc[4][4];
#pragma unroll
  for (int mt = 0; mt < 4; ++mt)
#pragma unroll
    for (int nt = 0; nt < 4; ++nt) acc[mt][nt] = (f32x4){0.f, 0.f, 0.f, 0.f};

  float bias4[4];
#pragma unroll
  for (int nt = 0; nt < 4; ++nt) bias4[nt] = bias[n0 + wc0 + (nt << 4) + l15];

  const int cbase = (w << 6) + l;

  for (int kt = 0; kt < 16; ++kt) {
    const int k0 = kt << 6;
    __syncthreads();
#pragma unroll
    for (int i = 0; i < 4; ++i) {
      const int c = cbase + (i << 8);
      const int r = c >> 3, kc = c & 7;
      char* ldsA = (char*)As + (((i << 2) + w) << 10);
      char* ldsB = (char*)Bs + (((i << 2) + w) << 10);
      gload16(X + (size_t)(m0 + r) * E_DIM + k0 + (kc << 3), ldsA);
      gload16(W + (size_t)(n0 + r) * E_DIM + k0 + (kc << 3), ldsB);
    }
    __syncthreads();
#pragma unroll
    for (int kh = 0; kh < 2; ++kh) {
      s16x8 af[4], bfr[4];
#pragma unroll
      for (int mt = 0; mt < 4; ++mt)
        af[mt] = *(const s16x8*)&As[(wr0 + (mt << 4) + l15) * 64 + (kh << 5) + (l4 << 3)];
#pragma unroll
      for (int nt = 0; nt < 4; ++nt)
        bfr[nt] = *(const s16x8*)&Bs[(wc0 + (nt << 4) + l15) * 64 + (kh << 5) + (l4 << 3)];
#pragma unroll
      for (int mt = 0; mt < 4; ++mt)
#pragma unroll
        for (int nt = 0; nt < 4; ++nt)
          acc[mt][nt] = __builtin_amdgcn_mfma_f32_16x16x32_bf16(
              af[mt], bfr[nt], acc[mt][nt], 0, 0, 0);
    }
  }

#pragma unroll
  for (int mt = 0; mt < 4; ++mt)
#pragma unroll
    for (int nt = 0; nt < 4; ++nt) {
      const int n = n0 + wc0 + (nt << 4) + l15;
      const int h = n >> 6, d = n & 63;
      const f32x4 c = acc[mt][nt];
#pragma unroll
      for (int r = 0; r < 4; ++r) {
        const int m = m0 + wr0 + (mt << 4) + (l4 << 2) + r;
        const int s = m >> 2, b = m & 3;
        O[((((size_t)b * H_NUM + h) * S_LEN) + s) * HD + d] =
            f2bf((c[r] + bias4[nt]) * scale);
      }
    }
}

// ---------------------------------------------------------------------------
// Output projection with hi/lo split A (validated R3/R4).
// ---------------------------------------------------------------------------
__global__ __launch_bounds__(256) void outp_mfma(
    const unsigned short* __restrict__ Ah, const unsigned short* __restrict__ Al,
    const unsigned short* __restrict__ W, const float* __restrict__ bias,
    float* __restrict__ out)
{
  __shared__ unsigned short Ahs[128 * 64];
  __shared__ unsigned short Als[128 * 64];
  __shared__ unsigned short Bs[128 * 64];

  const int tid = threadIdx.x;
  const int w = tid >> 6, l = tid & 63;
  const int l15 = l & 15, l4 = l >> 4;
  const int m0 = blockIdx.x << 7, n0 = blockIdx.y << 7;
  const int wr0 = (w >> 1) << 6, wc0 = (w & 1) << 6;

  f32x4 acc[4][4];
#pragma unroll
  for (int mt = 0; mt < 4; ++mt)
#pragma unroll
    for (int nt = 0; nt < 4; ++nt) acc[mt][nt] = (f32x4){0.f, 0.f, 0.f, 0.f};

  float bias4[4];
#pragma unroll
  for (int nt = 0; nt < 4; ++nt) bias4[nt] = bias[n0 + wc0 + (nt << 4) + l15];

  const int cbase = (w << 6) + l;

  for (int kt = 0; kt < 16; ++kt) {
    const int k0 = kt << 6;
    __syncthreads();
#pragma unroll
    for (int i = 0; i < 4; ++i) {
      const int c = cbase + (i << 8);
      const int r = c >> 3, kc = c & 7;
      char* ldsAh = (char*)Ahs + (((i << 2) + w) << 10);
      char* ldsAl = (char*)Als + (((i << 2) + w) << 10);
      char* ldsB  = (char*)Bs  + (((i << 2) + w) << 10);
      gload16(Ah + (size_t)(m0 + r) * E_DIM + k0 + (kc << 3), ldsAh);
      gload16(Al + (size_t)(m0 + r) * E_DIM + k0 + (kc << 3), ldsAl);
      gload16(W  + (size_t)(n0 + r) * E_DIM + k0 + (kc << 3), ldsB);
    }
    __syncthreads();
#pragma unroll
    for (int kh = 0; kh < 2; ++kh) {
      s16x8 ah[4], al[4], bfr[4];
      const int ko = (kh << 5) + (l4 << 3);
#pragma unroll
      for (int mt = 0; mt < 4; ++mt) {
        ah[mt] = *(const s16x8*)&Ahs[(wr0 + (mt << 4) + l15) * 64 + ko];
        al[mt] = *(const s16x8*)&Als[(wr0 + (mt << 4) + l15) * 64 + ko];
      }
#pragma unroll
      for (int nt = 0; nt < 4; ++nt)
        bfr[nt] = *(const s16x8*)&Bs[(wc0 + (nt << 4) + l15) * 64 + ko];
#pragma unroll
      for (int mt = 0; mt < 4; ++mt)
#pragma unroll
        for (int nt = 0; nt < 4; ++nt) {
          acc[mt][nt] = __builtin_amdgcn_mfma_f32_16x16x32_bf16(
              ah[mt], bfr[nt], acc[mt][nt], 0, 0, 0);
          acc[mt][nt] = __builtin_amdgcn_mfma_f32_16x16x32_bf16(
              al[mt], bfr[nt], acc[mt][nt], 0, 0, 0);
        }
    }
  }

#pragma unroll
  for (int mt = 0; mt < 4; ++mt)
#pragma unroll
    for (int nt = 0; nt < 4; ++nt) {
      const int n = n0 + wc0 + (nt << 4) + l15;
      const f32x4 c = acc[mt][nt];
#pragma unroll
      for (int r = 0; r < 4; ++r) {
        const int m = m0 + wr0 + (mt << 4) + (l4 << 2) + r;
        const int b = m >> 10, s = m & 1023;
        out[((size_t)s * B_SZ + b) * E_DIM + n] = c[r] + bias4[nt];
      }
    }
}

// ---------------------------------------------------------------------------
// bf16 MFMA flash attention (validated R4/R6 structure + T5 setprio).
// R8 delta: softmax 16-lane reduces via DPP row_ror butterfly (VALU pipe)
// instead of __shfl_xor (ds_swizzle -> LDS pipe).
// ---------------------------------------------------------------------------
__global__ __launch_bounds__(256) void attn_mfma(
    const unsigned short* __restrict__ Qb, const unsigned short* __restrict__ Kb,
    const unsigned short* __restrict__ Vb, const unsigned short* __restrict__ Rb,
    unsigned short* __restrict__ AOh, unsigned short* __restrict__ AOl)
{
  __shared__ unsigned short Ks[64 * 64];   // [j][d], slot = cb ^ (r&7)
  __shared__ unsigned short Rs[64 * 64];   // [r][d], slot = cb ^ (r&7)
  __shared__ unsigned short Vt[64 * 64];   // [d][j], slot = cb ^ (d&7) ^ ((d>>3)&7)
  __shared__ unsigned short Ps[64 * 64];   // [i][j], slot = cb ^ (i&7)
  __shared__ float band[64 * 132];         // ring: row i, slot 0..127

  const int tid = threadIdx.x;
  const int lane = tid & 63;
  const int w = tid >> 6;
  const int st = blockIdx.x & 15;
  const int bh = blockIdx.x >> 4;
  const int s0 = st << 6;
  const int bb = bh >> 4, hh = bh & 15;
  const size_t base = (size_t)bh * (S_LEN * HD);
  const int l15 = lane & 15, l4 = lane >> 4;
  const int rb_ = w << 4;                 // wave's q-row base

  // staging maps
  const int sr = tid >> 3, scb = tid & 7;          // K/R rows, chunk
  const int ksl = (scb ^ (sr & 7)) << 3;           // swizzled chunk slot
  const int jp = tid >> 3, vc = tid & 7;           // V: j-pair, d-chunk
  const int jc = jp >> 2, jlow = (jp & 3) << 1;

  const int rbase = 959 - s0;

  // Q fragments (A-operand: row=lane&15, k=(lane>>4)*8+e)
  s16x8 qf0, qf1;
  {
    const unsigned short* qp =
        Qb + base + (size_t)(s0 + rb_ + l15) * HD + (l4 << 3);
    qf0 = *(const s16x8*)(qp);
    qf1 = *(const s16x8*)(qp + 32);
  }

  f32x4 of[4];
  float mrow[4], lrow[4];
#pragma unroll
  for (int m = 0; m < 4; ++m) {
    of[m] = (f32x4){0.f, 0.f, 0.f, 0.f};
    mrow[m] = NEG_BIG; lrow[m] = 0.f;
  }

  // band MFMA + ring write for the block currently staged in Rs
#define BAND_MFMA(H0)                                                          \
  {                                                                            \
    f32x4 bq[4];                                                               \
    _Pragma("unroll") for (int rt = 0; rt < 4; ++rt)                           \
        bq[rt] = (f32x4){0.f, 0.f, 0.f, 0.f};                                  \
    __builtin_amdgcn_s_setprio(1);                                             \
    _Pragma("unroll") for (int kk = 0; kk < 2; ++kk) {                         \
      const s16x8 qv = kk ? qf1 : qf0;                                         \
      const int cb = l4 + (kk << 2);                                           \
      _Pragma("unroll") for (int rt = 0; rt < 4; ++rt) {                       \
        const int r = (rt << 4) + l15;                                         \
        const s16x8 rf = *(const s16x8*)&Rs[(r << 6) + ((cb ^ (r & 7)) << 3)]; \
        bq[rt] = __builtin_amdgcn_mfma_f32_16x16x32_bf16(qv, rf, bq[rt], 0, 0, 0); \
      }                                                                        \
    }                                                                          \
    __builtin_amdgcn_s_setprio(0);                                             \
    _Pragma("unroll") for (int rt = 0; rt < 4; ++rt)                           \
      _Pragma("unroll") for (int m = 0; m < 4; ++m)                            \
        band[(rb_ + (l4 << 2) + m) * 132 + (H0) + (rt << 4) + l15] = bq[rt][m];\
  }

  // ---- prologue: band blocks 0 and 1
  s16x8 Kr0, Kr1, Vr0, Vr1, Rr0, Rr1;
  {
    s16x8 tA0, tA1, tB0, tB1;
    tA0 = *(const s16x8*)(Rb + (size_t)clampg(rbase + sr) * HD + (scb << 3));
    tA1 = *(const s16x8*)(Rb + (size_t)clampg(rbase + 32 + sr) * HD + (scb << 3));
    tB0 = *(const s16x8*)(Rb + (size_t)clampg(rbase + 64 + sr) * HD + (scb << 3));
    tB1 = *(const s16x8*)(Rb + (size_t)clampg(rbase + 96 + sr) * HD + (scb << 3));
    *(s16x8*)&Rs[(sr << 6) + ksl] = tA0;
    *(s16x8*)&Rs[((sr + 32) << 6) + ksl] = tA1;
    __syncthreads();
    BAND_MFMA(0);
    // prefetch tile 0 K,V and R block 2
    Kr0 = *(const s16x8*)(Kb + base + (size_t)sr * HD + (scb << 3));
    Kr1 = *(const s16x8*)(Kb + base + (size_t)(32 + sr) * HD + (scb << 3));
    Vr0 = *(const s16x8*)(Vb + base + (size_t)(jp << 1) * HD + (vc << 3));
    Vr1 = *(const s16x8*)(Vb + base + (size_t)((jp << 1) + 1) * HD + (vc << 3));
    Rr0 = *(const s16x8*)(Rb + (size_t)clampg(rbase + 128 + sr) * HD + (scb << 3));
    Rr1 = *(const s16x8*)(Rb + (size_t)clampg(rbase + 160 + sr) * HD + (scb << 3));
    __syncthreads();               // all waves done reading Rs (block 0)
    *(s16x8*)&Rs[(sr << 6) + ksl] = tB0;
    *(s16x8*)&Rs[((sr + 32) << 6) + ksl] = tB1;
    __syncthreads();
    BAND_MFMA(64);
  }

  for (int tt = 0; tt < 16; ++tt) {
    const int t0 = tt << 6;
    __syncthreads();   // previous compute (and prologue BAND(64)) done with LDS

    // ---- stage prefetched regs -> LDS
    *(s16x8*)&Ks[(sr << 6) + ksl] = Kr0;
    *(s16x8*)&Ks[((sr + 32) << 6) + ksl] = Kr1;
    *(s16x8*)&Rs[(sr << 6) + ksl] = Rr0;
    *(s16x8*)&Rs[((sr + 32) << 6) + ksl] = Rr1;
#pragma unroll
    for (int e = 0; e < 8; ++e) {
      const int d = (vc << 3) + e;
      const int slot = jc ^ e ^ vc;
      const unsigned int pack = (unsigned int)(unsigned short)Vr0[e] |
                                ((unsigned int)(unsigned short)Vr1[e] << 16);
      *(unsigned int*)&Vt[(d << 6) + (slot << 3) + jlow] = pack;
    }
    __syncthreads();

    // ---- prefetch next tile (K,V) and R block tt+3
    if (tt < 15) {
      const int tn = t0 + 64;
      Kr0 = *(const s16x8*)(Kb + base + (size_t)(tn + sr) * HD + (scb << 3));
      Kr1 = *(const s16x8*)(Kb + base + (size_t)(tn + 32 + sr) * HD + (scb << 3));
      Vr0 = *(const s16x8*)(Vb + base + (size_t)(tn + (jp << 1)) * HD + (vc << 3));
      Vr1 = *(const s16x8*)(Vb + base + (size_t)(tn + (jp << 1) + 1) * HD + (vc << 3));
      const int gb = rbase + ((tt + 3) << 6) + sr;
      Rr0 = *(const s16x8*)(Rb + (size_t)clampg(gb) * HD + (scb << 3));
      Rr1 = *(const s16x8*)(Rb + (size_t)clampg(gb + 32) * HD + (scb << 3));
    }

    // ---- content MFMA
    f32x4 cf[4];
#pragma unroll
    for (int jt = 0; jt < 4; ++jt) cf[jt] = (f32x4){0.f, 0.f, 0.f, 0.f};
    __builtin_amdgcn_s_setprio(1);
#pragma unroll
    for (int kk = 0; kk < 2; ++kk) {
      const s16x8 qv = kk ? qf1 : qf0;
      const int cb = l4 + (kk << 2);
#pragma unroll
      for (int jt = 0; jt < 4; ++jt) {
        const int r = (jt << 4) + l15;
        const s16x8 kf = *(const s16x8*)&Ks[(r << 6) + ((cb ^ (r & 7)) << 3)];
        cf[jt] = __builtin_amdgcn_mfma_f32_16x16x32_bf16(qv, kf, cf[jt], 0, 0, 0);
      }
    }
    __builtin_amdgcn_s_setprio(0);

    // ---- online softmax with ring-band gather; P -> LDS (own rows)
#pragma unroll
    for (int m = 0; m < 4; ++m) {
      const int irow = rb_ + (l4 << 2) + m;
      const int bc = t0 + 63 - irow;
      const float* bp = &band[irow * 132];
      float sv[4];
#pragma unroll
      for (int jt = 0; jt < 4; ++jt)
        sv[jt] = cf[jt][m] + bp[(bc + (jt << 4) + l15) & 127];
      float mx = fmaxf(fmaxf(sv[0], sv[1]), fmaxf(sv[2], sv[3]));
      mx = rmax16(mx);
      const float mnew = fmaxf(mrow[m], mx);
      const float alpha = __expf(mrow[m] - mnew);
      float p[4], ls = 0.f;
#pragma unroll
      for (int jt = 0; jt < 4; ++jt) { p[jt] = __expf(sv[jt] - mnew); ls += p[jt]; }
      ls = rsum16(ls);
      lrow[m] = lrow[m] * alpha + ls;
      mrow[m] = mnew;
#pragma unroll
      for (int dt = 0; dt < 4; ++dt) of[dt][m] *= alpha;
#pragma unroll
      for (int jt = 0; jt < 4; ++jt) {
        const int col = (jt << 4) + l15;
        const int ch = col >> 3;
        Ps[(irow << 6) + ((ch ^ (irow & 7)) << 3) + (col & 7)] = f2bf(p[jt]);
      }
    }

    // ---- band MFMA for block tt+2 -> ring half (tt&1)  (wave-private rows)
    BAND_MFMA((tt & 1) << 6);

    // ---- PV: O += P @ V  (A = P own rows, B = Vt)
    __builtin_amdgcn_s_setprio(1);
#pragma unroll
    for (int kk = 0; kk < 2; ++kk) {
      const int cb = l4 + (kk << 2);
      const int pr = rb_ + l15;
      const s16x8 pf = *(const s16x8*)&Ps[(pr << 6) + ((cb ^ (pr & 7)) << 3)];
#pragma unroll
      for (int dt = 0; dt < 4; ++dt) {
        const int dr = (dt << 4) + l15;
        const int slot = cb ^ (dr & 7) ^ ((dt << 1) + (l15 >> 3));
        const s16x8 vf = *(const s16x8*)&Vt[(dr << 6) + (slot << 3)];
        of[dt] = __builtin_amdgcn_mfma_f32_16x16x32_bf16(pf, vf, of[dt], 0, 0, 0);
      }
    }
    __builtin_amdgcn_s_setprio(0);
  }

  // ---- epilogue: hi/lo bf16 split of normalized output, [B,S,E] e=h*64+d
#pragma unroll
  for (int m = 0; m < 4; ++m) {
    const float inv = 1.f / lrow[m];
    const int srow = s0 + rb_ + (l4 << 2) + m;
    const size_t off0 = ((size_t)bb * S_LEN + srow) * E_DIM + (hh << 6) + l15;
#pragma unroll
    for (int dt = 0; dt < 4; ++dt) {
      const float x = of[dt][m] * inv;
      const unsigned short hi = f2bf(x);
      AOh[off0 + (dt << 4)] = hi;
      AOl[off0 + (dt << 4)] = f2bf(x - bf2f(hi));
    }
  }
#undef BAND_MFMA
}

// ---------------------------------------------------------------------------
extern "C" void kernel_launch(void* const* d_in, const int* in_sizes, int n_in,
                              void* d_out, int out_size, void* d_ws, size_t ws_size,
                              hipStream_t stream) {
  (void)in_sizes; (void)n_in; (void)out_size; (void)ws_size;
  const float* query = (const float*)d_in[0];
  const float* key   = (const float*)d_in[1];
  const float* value = (const float*)d_in[2];
  const float* Wq = (const float*)d_in[3];
  const float* bq = (const float*)d_in[4];
  const float* Wk = (const float*)d_in[5];
  const float* bk = (const float*)d_in[6];
  const float* Wv = (const float*)d_in[7];
  const float* bv = (const float*)d_in[8];
  const float* Wo = (const float*)d_in[9];
  const float* bo = (const float*)d_in[10];
  const float* tbl = (const float*)d_in[11];

  const size_t per = (size_t)B_SZ * H_NUM * S_LEN * HD;   // 4,194,304 elems
  const size_t wsz = (size_t)E_DIM * E_DIM;               // 1,048,576 elems
  unsigned short* p = (unsigned short*)d_ws;
  unsigned short* wsQb = p; p += per;
  unsigned short* wsKb = p; p += per;
  unsigned short* wsVb = p; p += per;
  unsigned short* wsRb = p; p += 131072;
  unsigned short* wsXq = p; p += per;
  unsigned short* wsXk = p; p += per;
  unsigned short* wsXv = p; p += per;
  unsigned short* wsWq = p; p += wsz;
  unsigned short* wsWk = p; p += wsz;
  unsigned short* wsWv = p; p += wsz;
  unsigned short* wsWo = p; p += wsz;
  unsigned short* wsAh = p; p += per;
  unsigned short* wsAl = p; p += per;
  float* out = (float*)d_out;

  dim3 blk(256);
  hipLaunchKernelGGL(conv_all, dim3(8256), blk, 0, stream,
                     query, key, value, Wq, Wk, Wv, Wo, tbl,
                     wsXq, wsXk, wsXv, wsWq, wsWk, wsWv, wsWo, wsRb);
  hipLaunchKernelGGL(qkv_mfma, dim3(32, 8, 3), blk, 0, stream,
                     wsXq, wsXk, wsXv, wsWq, wsWk, wsWv, bq, bk, bv,
                     wsQb, wsKb, wsVb);
  hipLaunchKernelGGL(attn_mfma, dim3(1024), blk, 0, stream,
                     wsQb, wsKb, wsVb, wsRb, wsAh, wsAl);
  hipLaunchKernelGGL(outp_mfma, dim3(32, 8), blk, 0, stream,
                     wsAh, wsAl, wsWo, bo, out);
}